// Round 4
// baseline (4652.795 us; speedup 1.0000x reference)
//
#include <hip/hip_runtime.h>
#include <cstdint>
#include <cstddef>

// SingleLayerLSTM: B=128, T=2048, D=64, H=256, O=32.
// v14: structural change -> TLP. R1-R3 bounded the "exchange scheduling"
// family at <5% (spec-poll hoists, raw barriers, mid-D sampling all ~flat):
// with ONE 512-thread block per CU, all 8 waves share every stall (poll,
// barrier convoy, shfl dep-chains, transcendental chains) -> VALUBusy 52%.
// v14 splits each item-pair across 8 blocks of 256 threads (32 ch each):
//  - per-thread work UNCHANGED (80 weight pairs, 160 gate-fdot2/step);
//  - 512 blocks -> 2 INDEPENDENT groups per CU: one block's compute fills
//    the other's stall windows. Co-residency guaranteed by resources:
//    launch_bounds(256,2) caps VGPR<=256, LDS ~6KB/block, 8 waves/CU.
//  - XCD swizzle (grp = bid&63, o8 = bid>>6): a group's 8 blocks share
//    blockIdx%8 -> same XCD -> u rows L2-shared (v12 proved this works
//    via FETCH 531->169MB). Exchange stays agent-scope (XCD-agnostic).
//  - exchange protocol identical: xh[parity][item][pair] u64, tag s+1 in
//    hi32, 2 fp16 ch in lo32, relaxed agent atomics, 0xAA poison -> no
//    init, graph-replay-safe. Mid-D spec poll + retry backstop (v13).
//  - raw lgkm barriers (global ops in flight across barriers).

#define HH 256
#define DD 64
#define TT 2048
#define OO 32

typedef _Float16 f16x2 __attribute__((ext_vector_type(2)));

__device__ __forceinline__ f16x2 b2h(int v) { return __builtin_bit_cast(f16x2, v); }
__device__ __forceinline__ int h2b(f16x2 v) { return __builtin_bit_cast(int, v); }
__device__ __forceinline__ unsigned pk32(float a, float b) {
  f16x2 v; v.x = (_Float16)a; v.y = (_Float16)b;
  return __builtin_bit_cast(unsigned, v);
}

#if __has_builtin(__builtin_amdgcn_fdot2)
__device__ __forceinline__ float fdot2(f16x2 a, f16x2 b, float c) {
  return __builtin_amdgcn_fdot2(a, b, c, false);
}
#else
__device__ __forceinline__ float fdot2(f16x2 a, f16x2 b, float c) {
  return fmaf((float)a.y, (float)b.y, fmaf((float)a.x, (float)b.x, c));
}
#endif

__device__ __forceinline__ float frcp(float x) { return __builtin_amdgcn_rcpf(x); }
__device__ __forceinline__ float sigm(float x)  { return frcp(1.0f + __expf(-x)); }
__device__ __forceinline__ float tanhf_(float x){ return 1.0f - 2.0f * frcp(1.0f + __expf(2.0f * x)); }

// LDS-only drain + raw barrier: global loads/stores stay in flight.
#define BAR_LGKM() do { \
  asm volatile("s_waitcnt lgkmcnt(0)" ::: "memory"); \
  __builtin_amdgcn_s_barrier(); \
  asm volatile("" ::: "memory"); \
} while (0)

#define XOR_ADD8(x) do { \
  x += __shfl_xor(x, 1); x += __shfl_xor(x, 2); x += __shfl_xor(x, 4); \
} while (0)

// u(8 rows, 4 pairs/gate) + own-h(4 rows, 2 pairs/gate); overwrites F,I,Z,R
#define UOWN(X, F, I, Z, R) do { \
  const int4 uv_ = *(const int4*)&(X)[rq * 8]; \
  const int2 ov_ = *(const int2*)&(X)[64 + rq * 4]; \
  f16x2 u0_=b2h(uv_.x),u1_=b2h(uv_.y),u2_=b2h(uv_.z),u3_=b2h(uv_.w); \
  f16x2 o0_=b2h(ov_.x),o1_=b2h(ov_.y); \
  F = fdot2(b2h(w2u[ 0]),u0_,0.0f); F = fdot2(b2h(w2u[ 1]),u1_,F); \
  F = fdot2(b2h(w2u[ 2]),u2_,F);    F = fdot2(b2h(w2u[ 3]),u3_,F); \
  F = fdot2(b2h(w2o[ 0]),o0_,F);    F = fdot2(b2h(w2o[ 1]),o1_,F); \
  I = fdot2(b2h(w2u[ 4]),u0_,0.0f); I = fdot2(b2h(w2u[ 5]),u1_,I); \
  I = fdot2(b2h(w2u[ 6]),u2_,I);    I = fdot2(b2h(w2u[ 7]),u3_,I); \
  I = fdot2(b2h(w2o[ 2]),o0_,I);    I = fdot2(b2h(w2o[ 3]),o1_,I); \
  Z = fdot2(b2h(w2u[ 8]),u0_,0.0f); Z = fdot2(b2h(w2u[ 9]),u1_,Z); \
  Z = fdot2(b2h(w2u[10]),u2_,Z);    Z = fdot2(b2h(w2u[11]),u3_,Z); \
  Z = fdot2(b2h(w2o[ 4]),o0_,Z);    Z = fdot2(b2h(w2o[ 5]),o1_,Z); \
  R = fdot2(b2h(w2u[12]),u0_,0.0f); R = fdot2(b2h(w2u[13]),u1_,R); \
  R = fdot2(b2h(w2u[14]),u2_,R);    R = fdot2(b2h(w2u[15]),u3_,R); \
  R = fdot2(b2h(w2o[ 6]),o0_,R);    R = fdot2(b2h(w2o[ 7]),o1_,R); \
} while (0)

// partner-h (28 rows = 14 pairs/gate) accumulate into F,I,Z,R
#define PDOT(X, F, I, Z, R) do { \
  const int2* pp_ = (const int2*)&(X)[96 + rq * 28]; \
  int2 v0_=pp_[0],v1_=pp_[1],v2_=pp_[2],v3_=pp_[3],v4_=pp_[4],v5_=pp_[5],v6_=pp_[6]; \
  f16x2 h0_ =b2h(v0_.x),h1_ =b2h(v0_.y),h2_ =b2h(v1_.x),h3_ =b2h(v1_.y); \
  f16x2 h4_ =b2h(v2_.x),h5_ =b2h(v2_.y),h6_ =b2h(v3_.x),h7_ =b2h(v3_.y); \
  f16x2 h8_ =b2h(v4_.x),h9_ =b2h(v4_.y),h10_=b2h(v5_.x),h11_=b2h(v5_.y); \
  f16x2 h12_=b2h(v6_.x),h13_=b2h(v6_.y); \
  F=fdot2(b2h(w2p[ 0]),h0_,F); F=fdot2(b2h(w2p[ 1]),h1_,F); \
  F=fdot2(b2h(w2p[ 2]),h2_,F); F=fdot2(b2h(w2p[ 3]),h3_,F); \
  F=fdot2(b2h(w2p[ 4]),h4_,F); F=fdot2(b2h(w2p[ 5]),h5_,F); \
  F=fdot2(b2h(w2p[ 6]),h6_,F); F=fdot2(b2h(w2p[ 7]),h7_,F); \
  F=fdot2(b2h(w2p[ 8]),h8_,F); F=fdot2(b2h(w2p[ 9]),h9_,F); \
  F=fdot2(b2h(w2p[10]),h10_,F);F=fdot2(b2h(w2p[11]),h11_,F); \
  F=fdot2(b2h(w2p[12]),h12_,F);F=fdot2(b2h(w2p[13]),h13_,F); \
  I=fdot2(b2h(w2p[14]),h0_,I); I=fdot2(b2h(w2p[15]),h1_,I); \
  I=fdot2(b2h(w2p[16]),h2_,I); I=fdot2(b2h(w2p[17]),h3_,I); \
  I=fdot2(b2h(w2p[18]),h4_,I); I=fdot2(b2h(w2p[19]),h5_,I); \
  I=fdot2(b2h(w2p[20]),h6_,I); I=fdot2(b2h(w2p[21]),h7_,I); \
  I=fdot2(b2h(w2p[22]),h8_,I); I=fdot2(b2h(w2p[23]),h9_,I); \
  I=fdot2(b2h(w2p[24]),h10_,I);I=fdot2(b2h(w2p[25]),h11_,I); \
  I=fdot2(b2h(w2p[26]),h12_,I);I=fdot2(b2h(w2p[27]),h13_,I); \
  Z=fdot2(b2h(w2p[28]),h0_,Z); Z=fdot2(b2h(w2p[29]),h1_,Z); \
  Z=fdot2(b2h(w2p[30]),h2_,Z); Z=fdot2(b2h(w2p[31]),h3_,Z); \
  Z=fdot2(b2h(w2p[32]),h4_,Z); Z=fdot2(b2h(w2p[33]),h5_,Z); \
  Z=fdot2(b2h(w2p[34]),h6_,Z); Z=fdot2(b2h(w2p[35]),h7_,Z); \
  Z=fdot2(b2h(w2p[36]),h8_,Z); Z=fdot2(b2h(w2p[37]),h9_,Z); \
  Z=fdot2(b2h(w2p[38]),h10_,Z);Z=fdot2(b2h(w2p[39]),h11_,Z); \
  Z=fdot2(b2h(w2p[40]),h12_,Z);Z=fdot2(b2h(w2p[41]),h13_,Z); \
  R=fdot2(b2h(w2p[42]),h0_,R); R=fdot2(b2h(w2p[43]),h1_,R); \
  R=fdot2(b2h(w2p[44]),h2_,R); R=fdot2(b2h(w2p[45]),h3_,R); \
  R=fdot2(b2h(w2p[46]),h4_,R); R=fdot2(b2h(w2p[47]),h5_,R); \
  R=fdot2(b2h(w2p[48]),h6_,R); R=fdot2(b2h(w2p[49]),h7_,R); \
  R=fdot2(b2h(w2p[50]),h8_,R); R=fdot2(b2h(w2p[51]),h9_,R); \
  R=fdot2(b2h(w2p[52]),h10_,R);R=fdot2(b2h(w2p[53]),h11_,R); \
  R=fdot2(b2h(w2p[54]),h12_,R);R=fdot2(b2h(w2p[55]),h13_,R); \
} while (0)

// y-partials for one item from the permuted h region [64,320) of X
#define YPART(X, OUTSLOT) do { \
  const int2* hq_ = (const int2*)&(X)[64 + jc * 16]; \
  int2 h0_ = hq_[0], h1_ = hq_[1], h2_ = hq_[2], h3_ = hq_[3]; \
  const int4* wp_ = (const int4*)&wopk[(jc * 4 + o) * 8]; \
  int4 wa_ = wp_[0], wb_ = wp_[1]; \
  float ya_ = 0.0f; \
  ya_ = fdot2(b2h(wa_.x), b2h(h0_.x), ya_); \
  ya_ = fdot2(b2h(wa_.y), b2h(h0_.y), ya_); \
  ya_ = fdot2(b2h(wa_.z), b2h(h1_.x), ya_); \
  ya_ = fdot2(b2h(wa_.w), b2h(h1_.y), ya_); \
  ya_ = fdot2(b2h(wb_.x), b2h(h2_.x), ya_); \
  ya_ = fdot2(b2h(wb_.y), b2h(h2_.y), ya_); \
  ya_ = fdot2(b2h(wb_.z), b2h(h3_.x), ya_); \
  ya_ = fdot2(b2h(wb_.w), b2h(h3_.y), ya_); \
  OUTSLOT = ya_; \
} while (0)

__global__ __launch_bounds__(256, 2)
void lstm_oct(const float* __restrict__ u,    const float* __restrict__ x0,
              const float* __restrict__ kfiz, const float* __restrict__ bfiz,
              const float* __restrict__ kr,   const float* __restrict__ br,
              const float* __restrict__ wout, const float* __restrict__ bout,
              float* __restrict__ out, unsigned long long* __restrict__ xh)
{
  const int tid = threadIdx.x;
  // Swizzle: group grp's 8 member blocks are bids {grp + 64*o8} -> all have
  // bid%8 == grp%8 -> same XCD (u rows L2-shared). Bijective on [0,512).
  const int grp = blockIdx.x & 63;          // item pair: items 2grp, 2grp+1
  const int o8  = blockIdx.x >> 6;          // eighth: channels [o8*32, o8*32+32)
  const int c   = tid >> 3;                 // channel within eighth [0,32)
  const int rq  = tid & 7;                  // row slice [0,8)
  const int cg  = o8 * 32 + c;              // global channel

  // per (parity,item): [0,64) u | [64,96) own h | [96,320) partner h (pos order)
  __shared__ __align__(16) _Float16 uh[2][2][320];
  __shared__ float yred[2][2][4][17];
  __shared__ __align__(16) int wopk[512];

  // ---- register-resident weights (80 pairs, shared by both items) ----
  int w2u[16], w2o[8], w2p[56];
#pragma unroll
  for (int g = 0; g < 4; ++g) {
    const float* colp = (g < 3) ? (kfiz + g * HH + cg) : (kr + cg);
    const int cst = (g < 3) ? 3 * HH : HH;
#pragma unroll
    for (int k = 0; k < 4; ++k) {         // u rows rq*8 + [0,8)
      f16x2 v;
      v.x = (_Float16)colp[(rq * 8 + 2 * k    ) * cst];
      v.y = (_Float16)colp[(rq * 8 + 2 * k + 1) * cst];
      w2u[g * 4 + k] = h2b(v);
    }
#pragma unroll
    for (int k = 0; k < 2; ++k) {         // own rows o8*32 + rq*4 + [0,4)
      f16x2 v;
      v.x = (_Float16)colp[(DD + o8 * 32 + rq * 4 + 2 * k    ) * cst];
      v.y = (_Float16)colp[(DD + o8 * 32 + rq * 4 + 2 * k + 1) * cst];
      w2o[g * 2 + k] = h2b(v);
    }
#pragma unroll
    for (int m = 0; m < 14; ++m) {        // partner pos rows rq*28 + [0,28)
      const int j0 = rq * 28 + 2 * m, j1 = j0 + 1;
      const int r0 = DD + (j0 < o8 * 32 ? j0 : j0 + 32);
      const int r1 = DD + (j1 < o8 * 32 ? j1 : j1 + 32);
      f16x2 v;
      v.x = (_Float16)colp[r0 * cst];
      v.y = (_Float16)colp[r1 * cst];
      w2p[g * 14 + m] = h2b(v);
    }
  }
  const float bf_ = bfiz[0 * HH + cg];
  const float bi_ = bfiz[1 * HH + cg];
  const float bz_ = bfiz[2 * HH + cg];
  const float br_ = br[cg];

  // ---- W_out staged permuted (block's 4 out cols; item-invariant) ----
  for (int t = tid; t < 512; t += 256) {
    const int k = t & 7, o = (t >> 3) & 3, jc = t >> 5;
    const int pos0 = jc * 16 + 2 * k, pos1 = pos0 + 1;
    const int ch0 = (pos0 < 32) ? o8 * 32 + pos0
                                : ((pos0 - 32) < o8 * 32 ? pos0 - 32 : pos0);
    const int ch1 = (pos1 < 32) ? o8 * 32 + pos1
                                : ((pos1 - 32) < o8 * 32 ? pos1 - 32 : pos1);
    f16x2 v;
    v.x = (_Float16)wout[ch0 * OO + o8 * 4 + o];
    v.y = (_Float16)wout[ch1 * OO + o8 * 4 + o];
    wopk[t] = h2b(v);
  }
  const float bo = (tid >= 248) ? bout[o8 * 4 + ((tid - 248) & 3)] : 0.0f;

  // ---- state init ----
  float cs0 = x0[(size_t)(grp * 2 + 0) * 512 + 256 + cg];
  float cs1 = x0[(size_t)(grp * 2 + 1) * 512 + 256 + cg];
#pragma unroll
  for (int v = 0; v < 2; ++v) {    // h0: 2 items x 256 ch over 256 threads
    const int idx = tid + 256 * v;
    const int it = idx >> 8, ch = idx & 255;
    const int rel = ch - o8 * 32;
    const int pos = (rel >= 0 && rel < 32)
                        ? 64 + rel
                        : 96 + (ch < o8 * 32 ? ch : ch - 32);
    uh[0][it][pos] = (_Float16)x0[(size_t)(grp * 2 + it) * 512 + ch];
  }
  if (tid >= 224) {                // u_0: 32 lanes x float4
    const int j = tid - 224;       // it = j>>4, 4 floats at (j&15)*4
    const float4 uv = *(const float4*)&u[((size_t)(grp * 2 + (j >> 4)) * TT) * DD + (j & 15) * 4];
    f16x2 p0; p0.x = (_Float16)uv.x; p0.y = (_Float16)uv.y;
    f16x2 p1; p1.x = (_Float16)uv.z; p1.y = (_Float16)uv.w;
    int2 w; w.x = h2b(p0); w.y = h2b(p1);
    *(int2*)&uh[0][j >> 4][(j & 15) * 4] = w;
  }
  __syncthreads();

  float a0f, a0i, a0z, a0r, a1f, a1i, a1z, a1r;
  UOWN(uh[0][0], a0f, a0i, a0z, a0r);
  UOWN(uh[0][1], a1f, a1i, a1z, a1r);

  for (int s = 0; s < TT; ++s) {
    const int cur = s & 1, nxt = cur ^ 1;

    // u_{s+1} issued early (lanes 224..255, float4 each)
    float4 un;
    if (tid >= 224 && s + 1 < TT) {
      const int j = tid - 224;
      un = *(const float4*)&u[((size_t)(grp * 2 + (j >> 4)) * TT + s + 1) * DD + (j & 15) * 4];
    }

    // ---- A: partner dots, both items ----
    PDOT(uh[cur][0], a0f, a0i, a0z, a0r);
    PDOT(uh[cur][1], a1f, a1i, a1z, a1r);

    // ---- B: reduce + activations ----
    XOR_ADD8(a0f); XOR_ADD8(a0i); XOR_ADD8(a0z); XOR_ADD8(a0r);
    XOR_ADD8(a1f); XOR_ADD8(a1i); XOR_ADD8(a1z); XOR_ADD8(a1r);
    const float f0 = sigm(a0f + bf_), i0 = sigm(a0i + bi_);
    const float z0 = sigm(a0z + bz_), r0 = tanhf_(a0r + br_);
    cs0 = f0 * cs0 + i0 * r0;
    const float hn0 = z0 * tanhf_(cs0);
    const float f1 = sigm(a1f + bf_), i1 = sigm(a1i + bi_);
    const float z1 = sigm(a1z + bz_), r1 = tanhf_(a1r + br_);
    cs1 = f1 * cs1 + i1 * r1;
    const float hn1 = z1 * tanhf_(cs1);

    // ---- C: publish + own-h LDS + u_{s+1} LDS ----
    const float hn0n = __shfl_down(hn0, 8);   // channel c+1's value (rq kept)
    const float hn1n = __shfl_down(hn1, 8);
    if (rq == 0) {
      uh[nxt][0][64 + c] = (_Float16)hn0;
      uh[nxt][1][64 + c] = (_Float16)hn1;
      if (!(c & 1)) {
        const int pair = o8 * 16 + (c >> 1);
        const unsigned long long tag = (unsigned long long)(s + 1) << 32;
        const size_t ix = ((size_t)nxt << 14) + (size_t)(grp * 2 + 0) * 128 + pair;
        __hip_atomic_store(&xh[ix], tag | pk32(hn0, hn0n),
                           __ATOMIC_RELAXED, __HIP_MEMORY_SCOPE_AGENT);
        __hip_atomic_store(&xh[ix + 128], tag | pk32(hn1, hn1n),
                           __ATOMIC_RELAXED, __HIP_MEMORY_SCOPE_AGENT);
      }
    }
    if (tid >= 224 && s + 1 < TT) {
      const int j = tid - 224;
      f16x2 p0; p0.x = (_Float16)un.x; p0.y = (_Float16)un.y;
      f16x2 p1; p1.x = (_Float16)un.z; p1.y = (_Float16)un.w;
      int2 w; w.x = h2b(p0); w.y = h2b(p1);
      *(int2*)&uh[nxt][j >> 4][(j & 15) * 4] = w;
    }
    BAR_LGKM();   // B1: LDS drain only; publish stores stay in flight

    // ---- D: shadow work, spec poll issued MID-D ----
    if (s >= 2 && tid >= 248) {                       // store y_{s-2}
      const int it = (tid - 248) >> 2, o = (tid - 248) & 3;
      float ssum = bo;
#pragma unroll
      for (int k = 0; k < 16; ++k) ssum += yred[nxt][it][o][k];
      out[((size_t)(grp * 2 + it) * TT + (s - 2)) * OO + o8 * 4 + o] = ssum;
    }
    if (s >= 1 && tid < 128) {                        // y partials for s-1
      const int it = tid >> 6, idx = tid & 63;
      const int o = idx & 3, jc = idx >> 2;
      YPART(uh[cur][it], yred[cur][it][o][jc]);
    }
    unsigned long long pv = 0;
    const unsigned long long* pf = nullptr;
    if (tid < 224) {
      const int pit = (tid >= 112) ? 1 : 0;
      const int pj  = pit ? tid - 112 : tid;          // partner pair [0,112)
      const int pidx = (pj < o8 * 16) ? pj : pj + 16;
      pf = xh + ((size_t)nxt << 14) + (size_t)(grp * 2 + pit) * 128 + pidx;
    }
    if (s + 1 < TT) UOWN(uh[nxt][0], a0f, a0i, a0z, a0r);
    if (tid < 224) {
      // mid-D spec issue: samples IC after partner publishes are visible,
      // returns ~end of D. sc0 sc1 = system-scope, bypass L1+L2.
      asm volatile("global_load_dwordx2 %0, %1, off sc0 sc1"
                   : "=v"(pv) : "v"(pf));
    }
    if (s + 1 < TT) UOWN(uh[nxt][1], a1f, a1i, a1z, a1r);

    // ---- E: check spec; serial agent re-poll only if stale ----
    if (tid < 224) {
      asm volatile("s_waitcnt vmcnt(0)" : "+v"(pv) :: "memory");
      const unsigned want = (unsigned)(s + 1);
      while ((unsigned)(pv >> 32) != want)
        pv = __hip_atomic_load(pf, __ATOMIC_RELAXED, __HIP_MEMORY_SCOPE_AGENT);
      const int pit = (tid >= 112) ? 1 : 0;
      const int pj  = pit ? tid - 112 : tid;
      ((int*)&uh[nxt][pit][96])[pj] = (int)(unsigned)pv;
    }
    BAR_LGKM();   // B2: LDS drain only; y/out stores stay in flight
  }

  // ---- epilogue: y_{TT-2} from yred[1]; y_{TT-1} from uh[0] ----
  if (tid >= 248) {
    const int it = (tid - 248) >> 2, o = (tid - 248) & 3;
    float ssum = bo;
#pragma unroll
    for (int k = 0; k < 16; ++k) ssum += yred[1][it][o][k];
    out[((size_t)(grp * 2 + it) * TT + (TT - 2)) * OO + o8 * 4 + o] = ssum;
  }
  if (tid < 128) {
    const int it = tid >> 6, idx = tid & 63;
    const int o = idx & 3, jc = idx >> 2;
    YPART(uh[0][it], yred[0][it][o][jc]);
  }
  __syncthreads();
  if (tid >= 248) {
    const int it = (tid - 248) >> 2, o = (tid - 248) & 3;
    float ssum = bo;
#pragma unroll
    for (int k = 0; k < 16; ++k) ssum += yred[0][it][o][k];
    out[((size_t)(grp * 2 + it) * TT + (TT - 1)) * OO + o8 * 4 + o] = ssum;
  }
}

extern "C" void kernel_launch(void* const* d_in, const int* in_sizes, int n_in,
                              void* d_out, int out_size, void* d_ws, size_t ws_size,
                              hipStream_t stream) {
  const float* u    = (const float*)d_in[0];
  const float* x0   = (const float*)d_in[1];
  const float* kfiz = (const float*)d_in[2];
  const float* bfiz = (const float*)d_in[3];
  const float* kr   = (const float*)d_in[4];
  const float* br   = (const float*)d_in[5];
  const float* wout = (const float*)d_in[6];
  const float* bout = (const float*)d_in[7];
  float* out = (float*)d_out;
  // ws: xh[2 parity][128 item][128 pair] u64 = 256 KB. 0xAA poison -> tag
  // 0xAAAAAAAA never matches a version in [1,2048] -> no init, replay-safe.
  unsigned long long* xh = (unsigned long long*)d_ws;
  lstm_oct<<<dim3(512), dim3(256), 0, stream>>>(
      u, x0, kfiz, bfiz, kr, br, wout, bout, out, xh);
}

// Round 5
// 3810.801 us; speedup vs baseline: 1.2209x; 1.2209x over previous
//
#include <hip/hip_runtime.h>
#include <cstdint>
#include <cstddef>

// SingleLayerLSTM: B=128, T=2048, D=64, H=256, O=32.
// v15: v10/v13 shape (4-block groups, 64ch/block, 80 weight-pair VGPRs,
// mid-D spec poll) but 1 ITEM PER BLOCK -> 512 blocks x 512 threads.
// R4 lesson: v14's 8-block groups added exchange (7/8 import, max-of-8
// convoy) faster than TLP paid; and 256-thr blocks gave the SAME 8
// waves/CU. v15 instead doubles waves/CU to 16 via launch_bounds(512,4)
// (128-VGPR cap; pool: 16w x 64l x 128r x 4B = 512KB = exact fit) with
// the two co-resident blocks from INDEPENDENT groups -> one group's
// exchange stall is covered by the other's VALU work.
//  - weights are per-channel-slice: unmerging items costs 0 extra VGPRs
//    (still 80 pairs), halves per-thread work/step (80 fdot2).
//  - mapping: xcd = bid&7; j = bid>>3; group g = (bid&7)*16 + (j&15),
//    quarter q4 = j>>4. Group's 4 quarters share the XCD (u L2-shared,
//    proven v12); consecutive dispatches on a CU differ in group.
//  - exchange identical to v10/v13: xh[parity][item][pair] u64, tag s+1
//    hi32 + 2 fp16 ch lo32, relaxed agent atomics, 0xAA poison -> no
//    init, graph-replay safe. Mid-D spec poll + retry backstop.
//  - raw lgkm barriers (global ops stay in flight across barriers).

#define HH 256
#define DD 64
#define TT 2048
#define OO 32

typedef _Float16 f16x2 __attribute__((ext_vector_type(2)));

__device__ __forceinline__ f16x2 b2h(int v) { return __builtin_bit_cast(f16x2, v); }
__device__ __forceinline__ int h2b(f16x2 v) { return __builtin_bit_cast(int, v); }
__device__ __forceinline__ unsigned pk32(float a, float b) {
  f16x2 v; v.x = (_Float16)a; v.y = (_Float16)b;
  return __builtin_bit_cast(unsigned, v);
}

#if __has_builtin(__builtin_amdgcn_fdot2)
__device__ __forceinline__ float fdot2(f16x2 a, f16x2 b, float c) {
  return __builtin_amdgcn_fdot2(a, b, c, false);
}
#else
__device__ __forceinline__ float fdot2(f16x2 a, f16x2 b, float c) {
  return fmaf((float)a.y, (float)b.y, fmaf((float)a.x, (float)b.x, c));
}
#endif

__device__ __forceinline__ float frcp(float x) { return __builtin_amdgcn_rcpf(x); }
__device__ __forceinline__ float sigm(float x)  { return frcp(1.0f + __expf(-x)); }
__device__ __forceinline__ float tanhf_(float x){ return 1.0f - 2.0f * frcp(1.0f + __expf(2.0f * x)); }

// LDS-only drain + raw barrier: global loads/stores stay in flight.
#define BAR_LGKM() do { \
  asm volatile("s_waitcnt lgkmcnt(0)" ::: "memory"); \
  __builtin_amdgcn_s_barrier(); \
  asm volatile("" ::: "memory"); \
} while (0)

#define XOR_ADD8(x) do { \
  x += __shfl_xor(x, 1); x += __shfl_xor(x, 2); x += __shfl_xor(x, 4); \
} while (0)

// u(8 rows) + own-h(8 rows) partial; overwrites F,I,Z,R
#define UOWN(X, F, I, Z, R) do { \
  const int4 uv_ = *(const int4*)&(X)[rq * 8]; \
  const int4 ov_ = *(const int4*)&(X)[64 + rq * 8]; \
  f16x2 u0_=b2h(uv_.x),u1_=b2h(uv_.y),u2_=b2h(uv_.z),u3_=b2h(uv_.w); \
  f16x2 o0_=b2h(ov_.x),o1_=b2h(ov_.y),o2_=b2h(ov_.z),o3_=b2h(ov_.w); \
  F = fdot2(b2h(w2u[ 0]),u0_,0.0f); F = fdot2(b2h(w2u[ 1]),u1_,F); \
  F = fdot2(b2h(w2u[ 2]),u2_,F);    F = fdot2(b2h(w2u[ 3]),u3_,F); \
  F = fdot2(b2h(w2o[ 0]),o0_,F);    F = fdot2(b2h(w2o[ 1]),o1_,F); \
  F = fdot2(b2h(w2o[ 2]),o2_,F);    F = fdot2(b2h(w2o[ 3]),o3_,F); \
  I = fdot2(b2h(w2u[ 4]),u0_,0.0f); I = fdot2(b2h(w2u[ 5]),u1_,I); \
  I = fdot2(b2h(w2u[ 6]),u2_,I);    I = fdot2(b2h(w2u[ 7]),u3_,I); \
  I = fdot2(b2h(w2o[ 4]),o0_,I);    I = fdot2(b2h(w2o[ 5]),o1_,I); \
  I = fdot2(b2h(w2o[ 6]),o2_,I);    I = fdot2(b2h(w2o[ 7]),o3_,I); \
  Z = fdot2(b2h(w2u[ 8]),u0_,0.0f); Z = fdot2(b2h(w2u[ 9]),u1_,Z); \
  Z = fdot2(b2h(w2u[10]),u2_,Z);    Z = fdot2(b2h(w2u[11]),u3_,Z); \
  Z = fdot2(b2h(w2o[ 8]),o0_,Z);    Z = fdot2(b2h(w2o[ 9]),o1_,Z); \
  Z = fdot2(b2h(w2o[10]),o2_,Z);    Z = fdot2(b2h(w2o[11]),o3_,Z); \
  R = fdot2(b2h(w2u[12]),u0_,0.0f); R = fdot2(b2h(w2u[13]),u1_,R); \
  R = fdot2(b2h(w2u[14]),u2_,R);    R = fdot2(b2h(w2u[15]),u3_,R); \
  R = fdot2(b2h(w2o[12]),o0_,R);    R = fdot2(b2h(w2o[13]),o1_,R); \
  R = fdot2(b2h(w2o[14]),o2_,R);    R = fdot2(b2h(w2o[15]),o3_,R); \
} while (0)

// partner-h (24 rows) accumulate into F,I,Z,R
#define PDOT(X, F, I, Z, R) do { \
  const int4* pp_ = (const int4*)&(X)[128 + rq * 24]; \
  int4 v0_ = pp_[0], v1_ = pp_[1], v2_ = pp_[2]; \
  f16x2 h0_=b2h(v0_.x),h1_=b2h(v0_.y),h2_ =b2h(v0_.z),h3_ =b2h(v0_.w); \
  f16x2 h4_=b2h(v1_.x),h5_=b2h(v1_.y),h6_ =b2h(v1_.z),h7_ =b2h(v1_.w); \
  f16x2 h8_=b2h(v2_.x),h9_=b2h(v2_.y),h10_=b2h(v2_.z),h11_=b2h(v2_.w); \
  F=fdot2(b2h(w2p[ 0]),h0_,F); F=fdot2(b2h(w2p[ 1]),h1_,F); \
  F=fdot2(b2h(w2p[ 2]),h2_,F); F=fdot2(b2h(w2p[ 3]),h3_,F); \
  F=fdot2(b2h(w2p[ 4]),h4_,F); F=fdot2(b2h(w2p[ 5]),h5_,F); \
  F=fdot2(b2h(w2p[ 6]),h6_,F); F=fdot2(b2h(w2p[ 7]),h7_,F); \
  F=fdot2(b2h(w2p[ 8]),h8_,F); F=fdot2(b2h(w2p[ 9]),h9_,F); \
  F=fdot2(b2h(w2p[10]),h10_,F);F=fdot2(b2h(w2p[11]),h11_,F); \
  I=fdot2(b2h(w2p[12]),h0_,I); I=fdot2(b2h(w2p[13]),h1_,I); \
  I=fdot2(b2h(w2p[14]),h2_,I); I=fdot2(b2h(w2p[15]),h3_,I); \
  I=fdot2(b2h(w2p[16]),h4_,I); I=fdot2(b2h(w2p[17]),h5_,I); \
  I=fdot2(b2h(w2p[18]),h6_,I); I=fdot2(b2h(w2p[19]),h7_,I); \
  I=fdot2(b2h(w2p[20]),h8_,I); I=fdot2(b2h(w2p[21]),h9_,I); \
  I=fdot2(b2h(w2p[22]),h10_,I);I=fdot2(b2h(w2p[23]),h11_,I); \
  Z=fdot2(b2h(w2p[24]),h0_,Z); Z=fdot2(b2h(w2p[25]),h1_,Z); \
  Z=fdot2(b2h(w2p[26]),h2_,Z); Z=fdot2(b2h(w2p[27]),h3_,Z); \
  Z=fdot2(b2h(w2p[28]),h4_,Z); Z=fdot2(b2h(w2p[29]),h5_,Z); \
  Z=fdot2(b2h(w2p[30]),h6_,Z); Z=fdot2(b2h(w2p[31]),h7_,Z); \
  Z=fdot2(b2h(w2p[32]),h8_,Z); Z=fdot2(b2h(w2p[33]),h9_,Z); \
  Z=fdot2(b2h(w2p[34]),h10_,Z);Z=fdot2(b2h(w2p[35]),h11_,Z); \
  R=fdot2(b2h(w2p[36]),h0_,R); R=fdot2(b2h(w2p[37]),h1_,R); \
  R=fdot2(b2h(w2p[38]),h2_,R); R=fdot2(b2h(w2p[39]),h3_,R); \
  R=fdot2(b2h(w2p[40]),h4_,R); R=fdot2(b2h(w2p[41]),h5_,R); \
  R=fdot2(b2h(w2p[42]),h6_,R); R=fdot2(b2h(w2p[43]),h7_,R); \
  R=fdot2(b2h(w2p[44]),h8_,R); R=fdot2(b2h(w2p[45]),h9_,R); \
  R=fdot2(b2h(w2p[46]),h10_,R);R=fdot2(b2h(w2p[47]),h11_,R); \
} while (0)

// y-partials from the permuted h region of X
#define YPART(X, OUTSLOT) do { \
  const int2* hq_ = (const int2*)&(X)[64 + jc * 16]; \
  int2 h0_ = hq_[0], h1_ = hq_[1], h2_ = hq_[2], h3_ = hq_[3]; \
  const int4* wp_ = (const int4*)&wopk[(jc * 8 + o) * 8]; \
  int4 wa_ = wp_[0], wb_ = wp_[1]; \
  float ya_ = 0.0f; \
  ya_ = fdot2(b2h(wa_.x), b2h(h0_.x), ya_); \
  ya_ = fdot2(b2h(wa_.y), b2h(h0_.y), ya_); \
  ya_ = fdot2(b2h(wa_.z), b2h(h1_.x), ya_); \
  ya_ = fdot2(b2h(wa_.w), b2h(h1_.y), ya_); \
  ya_ = fdot2(b2h(wb_.x), b2h(h2_.x), ya_); \
  ya_ = fdot2(b2h(wb_.y), b2h(h2_.y), ya_); \
  ya_ = fdot2(b2h(wb_.z), b2h(h3_.x), ya_); \
  ya_ = fdot2(b2h(wb_.w), b2h(h3_.y), ya_); \
  OUTSLOT = ya_; \
} while (0)

__global__ __launch_bounds__(512, 4)
void lstm_solo(const float* __restrict__ u,    const float* __restrict__ x0,
               const float* __restrict__ kfiz, const float* __restrict__ bfiz,
               const float* __restrict__ kr,   const float* __restrict__ br,
               const float* __restrict__ wout, const float* __restrict__ bout,
               float* __restrict__ out, unsigned long long* __restrict__ xh)
{
  const int tid = threadIdx.x;
  // Mapping: xcd = bid&7 (round-robin dispatch); within an XCD its 64
  // blocks interleave 16 groups x 4 quarters so consecutive dispatches
  // on a CU are from different groups; group's quarters share the XCD.
  const int bid = blockIdx.x;
  const int j   = bid >> 3;
  const int g   = (bid & 7) * 16 + (j & 15);  // item [0,128)
  const int q4  = j >> 4;                     // quarter [0,4)
  const int c   = tid >> 3;                   // channel within quarter [0,64)
  const int rq  = tid & 7;                    // row slice [0,8)
  const int cg  = q4 * 64 + c;                // global channel

  // per parity: [0,64) u | [64,128) own h | [128,320) partner h (P-order)
  __shared__ __align__(16) _Float16 uh[2][320];
  __shared__ float yred[2][8][17];
  __shared__ __align__(16) int wopk[1024];

  // ---- register-resident weights (80 pairs) ----
  int w2u[16], w2o[16], w2p[48];
#pragma unroll
  for (int gg = 0; gg < 4; ++gg) {
    const float* colp = (gg < 3) ? (kfiz + gg * HH + cg) : (kr + cg);
    const int cst = (gg < 3) ? 3 * HH : HH;
#pragma unroll
    for (int k = 0; k < 4; ++k) {
      f16x2 v;
      v.x = (_Float16)colp[(rq * 8 + 2 * k    ) * cst];
      v.y = (_Float16)colp[(rq * 8 + 2 * k + 1) * cst];
      w2u[gg * 4 + k] = h2b(v);
      f16x2 w;
      w.x = (_Float16)colp[(DD + q4 * 64 + rq * 8 + 2 * k    ) * cst];
      w.y = (_Float16)colp[(DD + q4 * 64 + rq * 8 + 2 * k + 1) * cst];
      w2o[gg * 4 + k] = h2b(w);
    }
#pragma unroll
    for (int m = 0; m < 12; ++m) {
      const int j0 = rq * 24 + 2 * m, j1 = j0 + 1;
      const int r0 = DD + (j0 < q4 * 64 ? j0 : j0 + 64);
      const int r1 = DD + (j1 < q4 * 64 ? j1 : j1 + 64);
      f16x2 v;
      v.x = (_Float16)colp[r0 * cst];
      v.y = (_Float16)colp[r1 * cst];
      w2p[gg * 12 + m] = h2b(v);
    }
  }
  const float bf_ = bfiz[0 * HH + cg];
  const float bi_ = bfiz[1 * HH + cg];
  const float bz_ = bfiz[2 * HH + cg];
  const float br_ = br[cg];

  // ---- W_out staged permuted (block's 8 out cols) ----
  for (int t = tid; t < 1024; t += 512) {
    const int jc = t >> 6, o = (t >> 3) & 7, k = t & 7;
    const int pos0 = jc * 16 + 2 * k, pos1 = pos0 + 1;
    const int ch0 = (pos0 < 64) ? q4 * 64 + pos0
                                : ((pos0 - 64) < q4 * 64 ? pos0 - 64 : pos0);
    const int ch1 = (pos1 < 64) ? q4 * 64 + pos1
                                : ((pos1 - 64) < q4 * 64 ? pos1 - 64 : pos1);
    f16x2 v;
    v.x = (_Float16)wout[ch0 * OO + q4 * 8 + o];
    v.y = (_Float16)wout[ch1 * OO + q4 * 8 + o];
    wopk[t] = h2b(v);
  }
  const float bo = (tid >= 320 && tid < 328) ? bout[q4 * 8 + (tid - 320)] : 0.0f;

  // ---- state init ----
  float cs = x0[(size_t)g * 512 + 256 + cg];
  if (tid < 256) {   // h0, permuted
    const int ch = tid;
    const int pos = (ch >= q4 * 64 && ch < q4 * 64 + 64)
                        ? 64 + (ch - q4 * 64)
                        : 128 + (ch < q4 * 64 ? ch : ch - 64);
    uh[0][pos] = (_Float16)x0[(size_t)g * 512 + ch];
  }
  if (tid >= 448) {  // u_0
    const int l = tid - 448;
    uh[0][l] = (_Float16)u[((size_t)g * TT) * DD + l];
  }
  __syncthreads();

  float af, ai, az, ar;
  UOWN(uh[0], af, ai, az, ar);

  for (int s = 0; s < TT; ++s) {
    const int cur = s & 1, nxt = cur ^ 1;

    // u_{s+1} issued early (lanes 448..511)
    float un = 0.0f;
    if (tid >= 448 && s + 1 < TT) {
      const int l = tid - 448;
      un = u[((size_t)g * TT + s + 1) * DD + l];
    }

    // ---- A: partner dots ----
    PDOT(uh[cur], af, ai, az, ar);

    // ---- B: reduce + activations ----
    XOR_ADD8(af); XOR_ADD8(ai); XOR_ADD8(az); XOR_ADD8(ar);
    const float f0 = sigm(af + bf_), i0 = sigm(ai + bi_);
    const float z0 = sigm(az + bz_), r0 = tanhf_(ar + br_);
    cs = f0 * cs + i0 * r0;
    const float hn = z0 * tanhf_(cs);

    // ---- C: publish (u64, 2 ch/word) + own-h LDS + u_{s+1} LDS ----
    const float hnn = __shfl_down(hn, 8);   // channel c+1's value (rq kept)
    if (rq == 0) {
      uh[nxt][64 + c] = (_Float16)hn;
      if (!(c & 1)) {
        const int pair = q4 * 32 + (c >> 1);
        const unsigned long long tag = (unsigned long long)(s + 1) << 32;
        __hip_atomic_store(&xh[((size_t)nxt << 14) + (size_t)g * 128 + pair],
                           tag | pk32(hn, hnn),
                           __ATOMIC_RELAXED, __HIP_MEMORY_SCOPE_AGENT);
      }
    }
    if (tid >= 448 && s + 1 < TT) {
      const int l = tid - 448;
      uh[nxt][l] = (_Float16)un;
    }
    BAR_LGKM();   // B1: LDS drain only; publish stores stay in flight

    // ---- D: shadow work, spec poll issued MID-D ----
    if (s >= 2 && tid >= 320 && tid < 328) {          // store y_{s-2}
      const int o = tid - 320;
      float ssum = bo;
#pragma unroll
      for (int k = 0; k < 16; ++k) ssum += yred[nxt][o][k];
      out[((size_t)g * TT + (s - 2)) * OO + q4 * 8 + o] = ssum;
    }
    if (s >= 1 && tid >= 192 && tid < 320) {          // y partials for s-1
      const int idx = tid - 192;
      const int o = idx & 7, jc = idx >> 3;
      YPART(uh[cur], yred[cur][o][jc]);
    }
    unsigned long long pv = 0;
    const unsigned long long* pf = nullptr;
    if (tid < 96) {
      const int pidx = (tid < q4 * 32) ? tid : tid + 32;   // partner pair
      pf = xh + ((size_t)nxt << 14) + (size_t)g * 128 + pidx;
    }
    if (s + 1 < TT) {                                  // u+own partials, s+1
      UOWN(uh[nxt], af, ai, az, ar);
    }
    if (tid < 96) {
      // mid-D spec issue: samples IC after partner publishes are visible,
      // returns ~end of D. sc0 sc1 = system-scope, bypass L1+L2.
      asm volatile("global_load_dwordx2 %0, %1, off sc0 sc1"
                   : "=v"(pv) : "v"(pf));
    }

    // ---- E: check spec; serial agent re-poll only if stale ----
    if (tid < 96) {
      asm volatile("s_waitcnt vmcnt(0)" : "+v"(pv) :: "memory");
      const unsigned want = (unsigned)(s + 1);
      while ((unsigned)(pv >> 32) != want)
        pv = __hip_atomic_load(pf, __ATOMIC_RELAXED, __HIP_MEMORY_SCOPE_AGENT);
      ((int*)&uh[nxt][128])[tid] = (int)(unsigned)pv;
    }
    BAR_LGKM();   // B2: LDS drain only; y/out stores stay in flight
  }

  // ---- epilogue: y_{TT-2} from yred[1]; y_{TT-1} from uh[0] ----
  if (tid >= 320 && tid < 328) {
    const int o = tid - 320;
    float ssum = bo;
#pragma unroll
    for (int k = 0; k < 16; ++k) ssum += yred[1][o][k];
    out[((size_t)g * TT + (TT - 2)) * OO + q4 * 8 + o] = ssum;
  }
  if (tid >= 192 && tid < 320) {
    const int idx = tid - 192;
    const int o = idx & 7, jc = idx >> 3;
    YPART(uh[0], yred[0][o][jc]);
  }
  __syncthreads();
  if (tid >= 320 && tid < 328) {
    const int o = tid - 320;
    float ssum = bo;
#pragma unroll
    for (int k = 0; k < 16; ++k) ssum += yred[0][o][k];
    out[((size_t)g * TT + (TT - 1)) * OO + q4 * 8 + o] = ssum;
  }
}

extern "C" void kernel_launch(void* const* d_in, const int* in_sizes, int n_in,
                              void* d_out, int out_size, void* d_ws, size_t ws_size,
                              hipStream_t stream) {
  const float* u    = (const float*)d_in[0];
  const float* x0   = (const float*)d_in[1];
  const float* kfiz = (const float*)d_in[2];
  const float* bfiz = (const float*)d_in[3];
  const float* kr   = (const float*)d_in[4];
  const float* br   = (const float*)d_in[5];
  const float* wout = (const float*)d_in[6];
  const float* bout = (const float*)d_in[7];
  float* out = (float*)d_out;
  // ws: xh[2 parity][128 item][128 pair] u64 = 256 KB. 0xAA poison -> tag
  // 0xAAAAAAAA never matches a version in [1,2048] -> no init, replay-safe.
  unsigned long long* xh = (unsigned long long*)d_ws;
  lstm_solo<<<dim3(512), dim3(512), 0, stream>>>(
      u, x0, kfiz, bfiz, kr, br, wout, bout, out, xh);
}

// Round 7
// 3262.276 us; speedup vs baseline: 1.4262x; 1.1681x over previous
//
#include <hip/hip_runtime.h>
#include <cstdint>
#include <cstddef>

// SingleLayerLSTM: B=128, T=2048, D=64, H=256, O=32.
// v16b = v16 with the DPP builtin fixed (ctrl must be a constant integer
// expression -> template parameter instead of runtime arg).
// v16 = v13 + (1) XCD co-location swizzle + (2) DPP-based 8-lane reduce.
// R5 lesson: occupancy/TLP is dead — wall time = 2048 x latency chain of
// one group (VALUBusy stayed 52% while occupancy doubled). Attack the
// chain and fabric contention instead:
//  (1) v12's proven swizzle (FETCH 531->169MB there): group g2's 4 blocks
//      share blockIdx%8 -> same XCD. u rows L2-shared, less IC pressure.
//      Exchange stays agent-scope -> placement is perf-only, not corr.
//  (2) XOR_ADD8's 3 dependent ds_bpermute shuffles (~30-40cy + lgkm each,
//      x8 on the chain) -> 3 v_add via DPP: quad_perm xor1 (0xB1),
//      quad_perm xor2 (0x4E), row_half_mirror (0x141; lane^7 == cross-
//      quad fold after xor1+xor2 since each quad then holds the quad-sum).
//      Pure VALU, ~4cy/stage, no LDS pipe.
// Everything else identical to v13 (best verified: 3876us): 256 blocks x
// 512 thr, 2 items/block, 80 fp16-pair weight VGPRs, u64 tagged agent
// exchange (0xAA poison -> no init, replay-safe), mid-D spec poll + retry
// backstop, raw lgkm barriers.

#define HH 256
#define DD 64
#define TT 2048
#define OO 32

typedef _Float16 f16x2 __attribute__((ext_vector_type(2)));

__device__ __forceinline__ f16x2 b2h(int v) { return __builtin_bit_cast(f16x2, v); }
__device__ __forceinline__ int h2b(f16x2 v) { return __builtin_bit_cast(int, v); }
__device__ __forceinline__ unsigned pk32(float a, float b) {
  f16x2 v; v.x = (_Float16)a; v.y = (_Float16)b;
  return __builtin_bit_cast(unsigned, v);
}

#if __has_builtin(__builtin_amdgcn_fdot2)
__device__ __forceinline__ float fdot2(f16x2 a, f16x2 b, float c) {
  return __builtin_amdgcn_fdot2(a, b, c, false);
}
#else
__device__ __forceinline__ float fdot2(f16x2 a, f16x2 b, float c) {
  return fmaf((float)a.y, (float)b.y, fmaf((float)a.x, (float)b.x, c));
}
#endif

__device__ __forceinline__ float frcp(float x) { return __builtin_amdgcn_rcpf(x); }
__device__ __forceinline__ float sigm(float x)  { return frcp(1.0f + __expf(-x)); }
__device__ __forceinline__ float tanhf_(float x){ return 1.0f - 2.0f * frcp(1.0f + __expf(2.0f * x)); }

// LDS-only drain + raw barrier: global loads/stores stay in flight.
#define BAR_LGKM() do { \
  asm volatile("s_waitcnt lgkmcnt(0)" ::: "memory"); \
  __builtin_amdgcn_s_barrier(); \
  asm volatile("" ::: "memory"); \
} while (0)

// DPP xor-add within each 8-lane group (all lanes live; bound_ctrl=true).
// CTRL as template parameter: builtin requires constant integer exprs.
template <int CTRL>
__device__ __forceinline__ float dpp_add(float x) {
  const int t = __builtin_amdgcn_mov_dpp(__builtin_bit_cast(int, x),
                                         CTRL, 0xf, 0xf, true);
  return x + __builtin_bit_cast(float, t);
}
#define XOR_ADD8(x) do { \
  x = dpp_add<0xB1>(x);  /* quad_perm [1,0,3,2] : ^1 */ \
  x = dpp_add<0x4E>(x);  /* quad_perm [2,3,0,1] : ^2 */ \
  x = dpp_add<0x141>(x); /* row_half_mirror: ^7 == cross-quad fold */ \
} while (0)

// u(8 rows) + own-h(8 rows) partial for one item; overwrites F,I,Z,R
#define UOWN(X, F, I, Z, R) do { \
  const int4 uv_ = *(const int4*)&(X)[rq * 8]; \
  const int4 ov_ = *(const int4*)&(X)[64 + rq * 8]; \
  f16x2 u0_=b2h(uv_.x),u1_=b2h(uv_.y),u2_=b2h(uv_.z),u3_=b2h(uv_.w); \
  f16x2 o0_=b2h(ov_.x),o1_=b2h(ov_.y),o2_=b2h(ov_.z),o3_=b2h(ov_.w); \
  F = fdot2(b2h(w2u[ 0]),u0_,0.0f); F = fdot2(b2h(w2u[ 1]),u1_,F); \
  F = fdot2(b2h(w2u[ 2]),u2_,F);    F = fdot2(b2h(w2u[ 3]),u3_,F); \
  F = fdot2(b2h(w2o[ 0]),o0_,F);    F = fdot2(b2h(w2o[ 1]),o1_,F); \
  F = fdot2(b2h(w2o[ 2]),o2_,F);    F = fdot2(b2h(w2o[ 3]),o3_,F); \
  I = fdot2(b2h(w2u[ 4]),u0_,0.0f); I = fdot2(b2h(w2u[ 5]),u1_,I); \
  I = fdot2(b2h(w2u[ 6]),u2_,I);    I = fdot2(b2h(w2u[ 7]),u3_,I); \
  I = fdot2(b2h(w2o[ 4]),o0_,I);    I = fdot2(b2h(w2o[ 5]),o1_,I); \
  I = fdot2(b2h(w2o[ 6]),o2_,I);    I = fdot2(b2h(w2o[ 7]),o3_,I); \
  Z = fdot2(b2h(w2u[ 8]),u0_,0.0f); Z = fdot2(b2h(w2u[ 9]),u1_,Z); \
  Z = fdot2(b2h(w2u[10]),u2_,Z);    Z = fdot2(b2h(w2u[11]),u3_,Z); \
  Z = fdot2(b2h(w2o[ 8]),o0_,Z);    Z = fdot2(b2h(w2o[ 9]),o1_,Z); \
  Z = fdot2(b2h(w2o[10]),o2_,Z);    Z = fdot2(b2h(w2o[11]),o3_,Z); \
  R = fdot2(b2h(w2u[12]),u0_,0.0f); R = fdot2(b2h(w2u[13]),u1_,R); \
  R = fdot2(b2h(w2u[14]),u2_,R);    R = fdot2(b2h(w2u[15]),u3_,R); \
  R = fdot2(b2h(w2o[12]),o0_,R);    R = fdot2(b2h(w2o[13]),o1_,R); \
  R = fdot2(b2h(w2o[14]),o2_,R);    R = fdot2(b2h(w2o[15]),o3_,R); \
} while (0)

// partner-h (24 rows) accumulate into F,I,Z,R
#define PDOT(X, F, I, Z, R) do { \
  const int4* pp_ = (const int4*)&(X)[128 + rq * 24]; \
  int4 v0_ = pp_[0], v1_ = pp_[1], v2_ = pp_[2]; \
  f16x2 h0_=b2h(v0_.x),h1_=b2h(v0_.y),h2_ =b2h(v0_.z),h3_ =b2h(v0_.w); \
  f16x2 h4_=b2h(v1_.x),h5_=b2h(v1_.y),h6_ =b2h(v1_.z),h7_ =b2h(v1_.w); \
  f16x2 h8_=b2h(v2_.x),h9_=b2h(v2_.y),h10_=b2h(v2_.z),h11_=b2h(v2_.w); \
  F=fdot2(b2h(w2p[ 0]),h0_,F); F=fdot2(b2h(w2p[ 1]),h1_,F); \
  F=fdot2(b2h(w2p[ 2]),h2_,F); F=fdot2(b2h(w2p[ 3]),h3_,F); \
  F=fdot2(b2h(w2p[ 4]),h4_,F); F=fdot2(b2h(w2p[ 5]),h5_,F); \
  F=fdot2(b2h(w2p[ 6]),h6_,F); F=fdot2(b2h(w2p[ 7]),h7_,F); \
  F=fdot2(b2h(w2p[ 8]),h8_,F); F=fdot2(b2h(w2p[ 9]),h9_,F); \
  F=fdot2(b2h(w2p[10]),h10_,F);F=fdot2(b2h(w2p[11]),h11_,F); \
  I=fdot2(b2h(w2p[12]),h0_,I); I=fdot2(b2h(w2p[13]),h1_,I); \
  I=fdot2(b2h(w2p[14]),h2_,I); I=fdot2(b2h(w2p[15]),h3_,I); \
  I=fdot2(b2h(w2p[16]),h4_,I); I=fdot2(b2h(w2p[17]),h5_,I); \
  I=fdot2(b2h(w2p[18]),h6_,I); I=fdot2(b2h(w2p[19]),h7_,I); \
  I=fdot2(b2h(w2p[20]),h8_,I); I=fdot2(b2h(w2p[21]),h9_,I); \
  I=fdot2(b2h(w2p[22]),h10_,I);I=fdot2(b2h(w2p[23]),h11_,I); \
  Z=fdot2(b2h(w2p[24]),h0_,Z); Z=fdot2(b2h(w2p[25]),h1_,Z); \
  Z=fdot2(b2h(w2p[26]),h2_,Z); Z=fdot2(b2h(w2p[27]),h3_,Z); \
  Z=fdot2(b2h(w2p[28]),h4_,Z); Z=fdot2(b2h(w2p[29]),h5_,Z); \
  Z=fdot2(b2h(w2p[30]),h6_,Z); Z=fdot2(b2h(w2p[31]),h7_,Z); \
  Z=fdot2(b2h(w2p[32]),h8_,Z); Z=fdot2(b2h(w2p[33]),h9_,Z); \
  Z=fdot2(b2h(w2p[34]),h10_,Z);Z=fdot2(b2h(w2p[35]),h11_,Z); \
  R=fdot2(b2h(w2p[36]),h0_,R); R=fdot2(b2h(w2p[37]),h1_,R); \
  R=fdot2(b2h(w2p[38]),h2_,R); R=fdot2(b2h(w2p[39]),h3_,R); \
  R=fdot2(b2h(w2p[40]),h4_,R); R=fdot2(b2h(w2p[41]),h5_,R); \
  R=fdot2(b2h(w2p[42]),h6_,R); R=fdot2(b2h(w2p[43]),h7_,R); \
  R=fdot2(b2h(w2p[44]),h8_,R); R=fdot2(b2h(w2p[45]),h9_,R); \
  R=fdot2(b2h(w2p[46]),h10_,R);R=fdot2(b2h(w2p[47]),h11_,R); \
} while (0)

// y-partials for one item from the permuted h region of X
#define YPART(X, OUTSLOT) do { \
  const int2* hq_ = (const int2*)&(X)[64 + jc * 16]; \
  int2 h0_ = hq_[0], h1_ = hq_[1], h2_ = hq_[2], h3_ = hq_[3]; \
  const int4* wp_ = (const int4*)&wopk[(jc * 8 + o) * 8]; \
  int4 wa_ = wp_[0], wb_ = wp_[1]; \
  float ya_ = 0.0f; \
  ya_ = fdot2(b2h(wa_.x), b2h(h0_.x), ya_); \
  ya_ = fdot2(b2h(wa_.y), b2h(h0_.y), ya_); \
  ya_ = fdot2(b2h(wa_.z), b2h(h1_.x), ya_); \
  ya_ = fdot2(b2h(wa_.w), b2h(h1_.y), ya_); \
  ya_ = fdot2(b2h(wb_.x), b2h(h2_.x), ya_); \
  ya_ = fdot2(b2h(wb_.y), b2h(h2_.y), ya_); \
  ya_ = fdot2(b2h(wb_.z), b2h(h3_.x), ya_); \
  ya_ = fdot2(b2h(wb_.w), b2h(h3_.y), ya_); \
  OUTSLOT = ya_; \
} while (0)

__global__ __launch_bounds__(512, 2)
void lstm_pair(const float* __restrict__ u,    const float* __restrict__ x0,
               const float* __restrict__ kfiz, const float* __restrict__ bfiz,
               const float* __restrict__ kr,   const float* __restrict__ br,
               const float* __restrict__ wout, const float* __restrict__ bout,
               float* __restrict__ out, unsigned long long* __restrict__ xh)
{
  const int tid = threadIdx.x;
  // XCD swizzle (v12-proven): group g2's 4 members all share pb&7 ->
  // same XCD under round-robin dispatch. Bijective on [0,256).
  const int pb  = blockIdx.x;
  const int g2  = (pb & 7) * 8 + (pb >> 5);  // item pair: items 2g2, 2g2+1
  const int q4  = (pb >> 3) & 3;             // quarter
  const int c   = tid >> 3;                  // channel within quarter [0,64)
  const int rq  = tid & 7;                   // row slice
  const int cg  = q4 * 64 + c;               // global channel

  // per (parity,item): [0,64) u | [64,128) own h | [128,320) partner h (P-order)
  __shared__ __align__(16) _Float16 uh[2][2][320];
  __shared__ float yred[2][2][8][17];
  __shared__ __align__(16) int wopk[1024];

  // ---- register-resident weights (80 pairs, shared by both items) ----
  int w2u[16], w2o[16], w2p[48];
#pragma unroll
  for (int g = 0; g < 4; ++g) {
    const float* colp = (g < 3) ? (kfiz + g * HH + cg) : (kr + cg);
    const int cst = (g < 3) ? 3 * HH : HH;
#pragma unroll
    for (int k = 0; k < 4; ++k) {
      f16x2 v;
      v.x = (_Float16)colp[(rq * 8 + 2 * k    ) * cst];
      v.y = (_Float16)colp[(rq * 8 + 2 * k + 1) * cst];
      w2u[g * 4 + k] = h2b(v);
      f16x2 w;
      w.x = (_Float16)colp[(DD + q4 * 64 + rq * 8 + 2 * k    ) * cst];
      w.y = (_Float16)colp[(DD + q4 * 64 + rq * 8 + 2 * k + 1) * cst];
      w2o[g * 4 + k] = h2b(w);
    }
#pragma unroll
    for (int m = 0; m < 12; ++m) {
      const int j0 = rq * 24 + 2 * m, j1 = j0 + 1;
      const int r0 = DD + (j0 < q4 * 64 ? j0 : j0 + 64);
      const int r1 = DD + (j1 < q4 * 64 ? j1 : j1 + 64);
      f16x2 v;
      v.x = (_Float16)colp[r0 * cst];
      v.y = (_Float16)colp[r1 * cst];
      w2p[g * 12 + m] = h2b(v);
    }
  }
  const float bf_ = bfiz[0 * HH + cg];
  const float bi_ = bfiz[1 * HH + cg];
  const float bz_ = bfiz[2 * HH + cg];
  const float br_ = br[cg];

  // ---- W_out staged permuted (block's 8 out cols; item-invariant) ----
  for (int t = tid; t < 1024; t += 512) {
    const int jc = t >> 6, o = (t >> 3) & 7, k = t & 7;
    const int pos0 = jc * 16 + 2 * k, pos1 = pos0 + 1;
    const int ch0 = (pos0 < 64) ? q4 * 64 + pos0
                                : ((pos0 - 64) < q4 * 64 ? pos0 - 64 : pos0);
    const int ch1 = (pos1 < 64) ? q4 * 64 + pos1
                                : ((pos1 - 64) < q4 * 64 ? pos1 - 64 : pos1);
    f16x2 v;
    v.x = (_Float16)wout[ch0 * OO + q4 * 8 + o];
    v.y = (_Float16)wout[ch1 * OO + q4 * 8 + o];
    wopk[t] = h2b(v);
  }
  const float bo = (tid >= 448 && tid < 464) ? bout[q4 * 8 + ((tid - 448) & 7)] : 0.0f;

  // ---- state init ----
  float cs0 = x0[(size_t)(g2 * 2 + 0) * 512 + 256 + cg];
  float cs1 = x0[(size_t)(g2 * 2 + 1) * 512 + 256 + cg];
  {  // h0, permuted; all 512 lanes cover 2 items x 256 ch
    const int it = tid >> 8, ch = tid & 255;
    const int pos = (ch >= q4 * 64 && ch < q4 * 64 + 64)
                        ? 64 + (ch - q4 * 64)
                        : 128 + (ch < q4 * 64 ? ch : ch - 64);
    uh[0][it][pos] = (_Float16)x0[(size_t)(g2 * 2 + it) * 512 + ch];
  }
  if (tid >= 192 && tid < 320) {   // u_0
    const int l = tid - 192;
    uh[0][l >> 6][l & 63] = (_Float16)u[((size_t)(g2 * 2 + (l >> 6)) * TT) * DD + (l & 63)];
  }
  __syncthreads();

  float a0f, a0i, a0z, a0r, a1f, a1i, a1z, a1r;
  UOWN(uh[0][0], a0f, a0i, a0z, a0r);
  UOWN(uh[0][1], a1f, a1i, a1z, a1r);

  for (int s = 0; s < TT; ++s) {
    const int cur = s & 1, nxt = cur ^ 1;

    // u_{s+1} issued early (lanes 192..319)
    float un = 0.0f;
    if (tid >= 192 && tid < 320 && s + 1 < TT) {
      const int l = tid - 192;
      un = u[((size_t)(g2 * 2 + (l >> 6)) * TT + s + 1) * DD + (l & 63)];
    }

    // ---- A: partner dots, both items ----
    PDOT(uh[cur][0], a0f, a0i, a0z, a0r);
    PDOT(uh[cur][1], a1f, a1i, a1z, a1r);

    // ---- B: reduce (DPP) + activations ----
    XOR_ADD8(a0f); XOR_ADD8(a0i); XOR_ADD8(a0z); XOR_ADD8(a0r);
    XOR_ADD8(a1f); XOR_ADD8(a1i); XOR_ADD8(a1z); XOR_ADD8(a1r);
    const float f0 = sigm(a0f + bf_), i0 = sigm(a0i + bi_);
    const float z0 = sigm(a0z + bz_), r0 = tanhf_(a0r + br_);
    cs0 = f0 * cs0 + i0 * r0;
    const float hn0 = z0 * tanhf_(cs0);
    const float f1 = sigm(a1f + bf_), i1 = sigm(a1i + bi_);
    const float z1 = sigm(a1z + bz_), r1 = tanhf_(a1r + br_);
    cs1 = f1 * cs1 + i1 * r1;
    const float hn1 = z1 * tanhf_(cs1);

    // ---- C: publish (u64, 2 ch/word) + own-h LDS + u_{s+1} LDS ----
    const float hn0n = __shfl_down(hn0, 8);   // channel c+1's value (rq kept)
    const float hn1n = __shfl_down(hn1, 8);
    if (rq == 0) {
      uh[nxt][0][64 + c] = (_Float16)hn0;
      uh[nxt][1][64 + c] = (_Float16)hn1;
      if (!(c & 1)) {
        const int pair = q4 * 32 + (c >> 1);
        const unsigned long long tag = (unsigned long long)(s + 1) << 32;
        __hip_atomic_store(&xh[((size_t)nxt * 128 + g2 * 2 + 0) * 128 + pair],
                           tag | pk32(hn0, hn0n),
                           __ATOMIC_RELAXED, __HIP_MEMORY_SCOPE_AGENT);
        __hip_atomic_store(&xh[((size_t)nxt * 128 + g2 * 2 + 1) * 128 + pair],
                           tag | pk32(hn1, hn1n),
                           __ATOMIC_RELAXED, __HIP_MEMORY_SCOPE_AGENT);
      }
    }
    if (tid >= 192 && tid < 320 && s + 1 < TT) {
      const int l = tid - 192;
      uh[nxt][l >> 6][l & 63] = (_Float16)un;
    }
    BAR_LGKM();   // B1: LDS drain only; publish stores stay in flight

    // ---- D: shadow work, spec poll issued MID-D ----
    if (s >= 2 && tid >= 448 && tid < 464) {          // store y_{s-2}
      const int it = (tid - 448) >> 3, o = (tid - 448) & 7;
      float ssum = bo;
#pragma unroll
      for (int k = 0; k < 16; ++k) ssum += yred[nxt][it][o][k];
      out[((size_t)(g2 * 2 + it) * TT + (s - 2)) * OO + q4 * 8 + o] = ssum;
    }
    if (s >= 1 && tid >= 192 && tid < 448) {          // y partials for s-1
      const int l = tid - 192, it = l >> 7, idx = l & 127;
      const int o = idx & 7, jc = idx >> 3;
      YPART(uh[cur][it], yred[cur][it][o][jc]);
    }
    unsigned long long pv = 0;
    const unsigned long long* pf = nullptr;
    if (tid < 192) {
      const int pit = (tid >= 96) ? 1 : 0;
      const int pj  = pit ? tid - 96 : tid;
      const int pidx = (pj < q4 * 32) ? pj : pj + 32;
      pf = xh + ((size_t)nxt << 14) + (size_t)(g2 * 2 + pit) * 128 + pidx;
    }
    if (s + 1 < TT) {                                  // u+own partials s+1, item0
      UOWN(uh[nxt][0], a0f, a0i, a0z, a0r);
    }
    if (tid < 192) {
      // mid-D spec issue: samples IC after partner publishes are visible,
      // returns ~end of D. sc0 sc1 = system-scope, bypass L1+L2.
      asm volatile("global_load_dwordx2 %0, %1, off sc0 sc1"
                   : "=v"(pv) : "v"(pf));
    }
    if (s + 1 < TT) {                                  // u+own partials s+1, item1
      UOWN(uh[nxt][1], a1f, a1i, a1z, a1r);
    }

    // ---- E: check spec; serial agent re-poll only if stale ----
    if (tid < 192) {
      asm volatile("s_waitcnt vmcnt(0)" : "+v"(pv) :: "memory");
      const unsigned want = (unsigned)(s + 1);
      while ((unsigned)(pv >> 32) != want)
        pv = __hip_atomic_load(pf, __ATOMIC_RELAXED, __HIP_MEMORY_SCOPE_AGENT);
      const int pit = (tid >= 96) ? 1 : 0;
      const int pj  = pit ? tid - 96 : tid;
      ((int*)&uh[nxt][pit][128])[pj] = (int)(unsigned)pv;
    }
    BAR_LGKM();   // B2: LDS drain only; y/out stores stay in flight
  }

  // ---- epilogue: y_{TT-2} from yred[1]; y_{TT-1} from uh[0] ----
  if (tid >= 448 && tid < 464) {
    const int it = (tid - 448) >> 3, o = (tid - 448) & 7;
    float ssum = bo;
#pragma unroll
    for (int k = 0; k < 16; ++k) ssum += yred[1][it][o][k];
    out[((size_t)(g2 * 2 + it) * TT + (TT - 2)) * OO + q4 * 8 + o] = ssum;
  }
  if (tid >= 192 && tid < 448) {
    const int l = tid - 192, it = l >> 7, idx = l & 127;
    const int o = idx & 7, jc = idx >> 3;
    YPART(uh[0][it], yred[0][it][o][jc]);
  }
  __syncthreads();
  if (tid >= 448 && tid < 464) {
    const int it = (tid - 448) >> 3, o = (tid - 448) & 7;
    float ssum = bo;
#pragma unroll
    for (int k = 0; k < 16; ++k) ssum += yred[0][it][o][k];
    out[((size_t)(g2 * 2 + it) * TT + (TT - 1)) * OO + q4 * 8 + o] = ssum;
  }
}

extern "C" void kernel_launch(void* const* d_in, const int* in_sizes, int n_in,
                              void* d_out, int out_size, void* d_ws, size_t ws_size,
                              hipStream_t stream) {
  const float* u    = (const float*)d_in[0];
  const float* x0   = (const float*)d_in[1];
  const float* kfiz = (const float*)d_in[2];
  const float* bfiz = (const float*)d_in[3];
  const float* kr   = (const float*)d_in[4];
  const float* br   = (const float*)d_in[5];
  const float* wout = (const float*)d_in[6];
  const float* bout = (const float*)d_in[7];
  float* out = (float*)d_out;
  // ws: xh[2 parity][128 item][128 pair] u64 = 256 KB. 0xAA poison -> tag
  // 0xAAAAAAAA never matches a version in [1,2048] -> no init, replay-safe.
  unsigned long long* xh = (unsigned long long*)d_ws;
  lstm_pair<<<dim3(256), dim3(512), 0, stream>>>(
      u, x0, kfiz, bfiz, kr, br, wout, bout, out, xh);
}

// Round 8
// 3024.991 us; speedup vs baseline: 1.5381x; 1.0784x over previous
//
#include <hip/hip_runtime.h>
#include <cstdint>
#include <cstddef>

// SingleLayerLSTM: B=128, T=2048, D=64, H=256, O=32.
// v17: group width 4 -> 2. R7 confirmed the model (swizzle+DPP: 3876->3262,
// FETCH 531->169MB, VALUBusy 52->67): remaining ~1300cy/step is exchange
// import + convoy. Group-width trend is monotone (8 << 4), so go to 2:
// 256 blocks x 512 thr, ONE item per 2 blocks, 128 ch/block.
//  - per-thread gate work UNCHANGED (160 fdot2): c=tid>>2 (128 ch),
//    rq=tid&3 (4 row slices of 80 rows); weights 160 pairs (~210 VGPR,
//    fits launch_bounds(512,2)'s 256 cap -> still 8 waves/CU).
//  - import halves: 64 u64 polls (wave 0 only) vs 192; convoy max-of-2.
//  - reduce: 4-lane XOR_ADD -> 2 DPP stages.
//  - XCD swizzle kept: group g's blocks are pb and pb+128 -> same pb&7
//    -> same XCD (R7-proven FETCH signature). Perf-only assumption.
//  - exchange protocol identical (tagged u64, relaxed agent atomics,
//    0xAA poison -> no init, graph-replay safe); mid-D spec poll + retry
//    backstop; raw lgkm barriers (global ops in flight across barriers).
// LDS per parity: [0,64) u | [64,192) own h | [192,320) partner h.

#define HH 256
#define DD 64
#define TT 2048
#define OO 32

typedef _Float16 f16x2 __attribute__((ext_vector_type(2)));

__device__ __forceinline__ f16x2 b2h(int v) { return __builtin_bit_cast(f16x2, v); }
__device__ __forceinline__ int h2b(f16x2 v) { return __builtin_bit_cast(int, v); }
__device__ __forceinline__ unsigned pk32(float a, float b) {
  f16x2 v; v.x = (_Float16)a; v.y = (_Float16)b;
  return __builtin_bit_cast(unsigned, v);
}

#if __has_builtin(__builtin_amdgcn_fdot2)
__device__ __forceinline__ float fdot2(f16x2 a, f16x2 b, float c) {
  return __builtin_amdgcn_fdot2(a, b, c, false);
}
#else
__device__ __forceinline__ float fdot2(f16x2 a, f16x2 b, float c) {
  return fmaf((float)a.y, (float)b.y, fmaf((float)a.x, (float)b.x, c));
}
#endif

__device__ __forceinline__ float frcp(float x) { return __builtin_amdgcn_rcpf(x); }
__device__ __forceinline__ float sigm(float x)  { return frcp(1.0f + __expf(-x)); }
__device__ __forceinline__ float tanhf_(float x){ return 1.0f - 2.0f * frcp(1.0f + __expf(2.0f * x)); }

// LDS-only drain + raw barrier: global loads/stores stay in flight.
#define BAR_LGKM() do { \
  asm volatile("s_waitcnt lgkmcnt(0)" ::: "memory"); \
  __builtin_amdgcn_s_barrier(); \
  asm volatile("" ::: "memory"); \
} while (0)

// DPP xor-add (ctrl must be constant -> template). bound_ctrl=true.
template <int CTRL>
__device__ __forceinline__ float dpp_add(float x) {
  const int t = __builtin_amdgcn_mov_dpp(__builtin_bit_cast(int, x),
                                         CTRL, 0xf, 0xf, true);
  return x + __builtin_bit_cast(float, t);
}
// 4-lane group (one quad): ^1 then ^2.
#define XOR_ADD4(x) do { \
  x = dpp_add<0xB1>(x);  /* quad_perm [1,0,3,2] : ^1 */ \
  x = dpp_add<0x4E>(x);  /* quad_perm [2,3,0,1] : ^2 */ \
} while (0)

// u(16 rows = 8 pairs/gate) + own-h(32 rows = 16 pairs/gate); overwrites F,I,Z,R
#define UOWN(X, F, I, Z, R) do { \
  int uv_[8], ov_[16]; \
  *(int4*)&uv_[0] = ((const int4*)&(X)[rq * 16])[0]; \
  *(int4*)&uv_[4] = ((const int4*)&(X)[rq * 16])[1]; \
  *(int4*)&ov_[0]  = ((const int4*)&(X)[64 + rq * 32])[0]; \
  *(int4*)&ov_[4]  = ((const int4*)&(X)[64 + rq * 32])[1]; \
  *(int4*)&ov_[8]  = ((const int4*)&(X)[64 + rq * 32])[2]; \
  *(int4*)&ov_[12] = ((const int4*)&(X)[64 + rq * 32])[3]; \
  float a0_ = 0.0f, a1_ = 0.0f, a2_ = 0.0f, a3_ = 0.0f; \
  _Pragma("unroll") for (int k_ = 0; k_ < 8; ++k_) { \
    a0_ = fdot2(b2h(w2u[ 0 + k_]), b2h(uv_[k_]), a0_); \
    a1_ = fdot2(b2h(w2u[ 8 + k_]), b2h(uv_[k_]), a1_); \
    a2_ = fdot2(b2h(w2u[16 + k_]), b2h(uv_[k_]), a2_); \
    a3_ = fdot2(b2h(w2u[24 + k_]), b2h(uv_[k_]), a3_); \
  } \
  _Pragma("unroll") for (int k_ = 0; k_ < 16; ++k_) { \
    a0_ = fdot2(b2h(w2o[ 0 + k_]), b2h(ov_[k_]), a0_); \
    a1_ = fdot2(b2h(w2o[16 + k_]), b2h(ov_[k_]), a1_); \
    a2_ = fdot2(b2h(w2o[32 + k_]), b2h(ov_[k_]), a2_); \
    a3_ = fdot2(b2h(w2o[48 + k_]), b2h(ov_[k_]), a3_); \
  } \
  F = a0_; I = a1_; Z = a2_; R = a3_; \
} while (0)

// partner-h (32 rows = 16 pairs/gate) accumulate into F,I,Z,R
#define PDOT(X, F, I, Z, R) do { \
  int pv_[16]; \
  *(int4*)&pv_[0]  = ((const int4*)&(X)[192 + rq * 32])[0]; \
  *(int4*)&pv_[4]  = ((const int4*)&(X)[192 + rq * 32])[1]; \
  *(int4*)&pv_[8]  = ((const int4*)&(X)[192 + rq * 32])[2]; \
  *(int4*)&pv_[12] = ((const int4*)&(X)[192 + rq * 32])[3]; \
  _Pragma("unroll") for (int k_ = 0; k_ < 16; ++k_) { \
    F = fdot2(b2h(w2p[ 0 + k_]), b2h(pv_[k_]), F); \
    I = fdot2(b2h(w2p[16 + k_]), b2h(pv_[k_]), I); \
    Z = fdot2(b2h(w2p[32 + k_]), b2h(pv_[k_]), Z); \
    R = fdot2(b2h(w2p[48 + k_]), b2h(pv_[k_]), R); \
  } \
} while (0)

// y-partials: h LDS positions [64,320), chunk jc of 16 elems, out col o.
#define YPART(X, OUTSLOT) do { \
  const int2* hq_ = (const int2*)&(X)[64 + jc * 16]; \
  int2 h0_ = hq_[0], h1_ = hq_[1], h2_ = hq_[2], h3_ = hq_[3]; \
  const int4* wp_ = (const int4*)&wopk[(jc * 16 + o) * 8]; \
  int4 wa_ = wp_[0], wb_ = wp_[1]; \
  float ya_ = 0.0f; \
  ya_ = fdot2(b2h(wa_.x), b2h(h0_.x), ya_); \
  ya_ = fdot2(b2h(wa_.y), b2h(h0_.y), ya_); \
  ya_ = fdot2(b2h(wa_.z), b2h(h1_.x), ya_); \
  ya_ = fdot2(b2h(wa_.w), b2h(h1_.y), ya_); \
  ya_ = fdot2(b2h(wb_.x), b2h(h2_.x), ya_); \
  ya_ = fdot2(b2h(wb_.y), b2h(h2_.y), ya_); \
  ya_ = fdot2(b2h(wb_.z), b2h(h3_.x), ya_); \
  ya_ = fdot2(b2h(wb_.w), b2h(h3_.y), ya_); \
  OUTSLOT = ya_; \
} while (0)

__global__ __launch_bounds__(512, 2)
void lstm_half(const float* __restrict__ u,    const float* __restrict__ x0,
               const float* __restrict__ kfiz, const float* __restrict__ bfiz,
               const float* __restrict__ kr,   const float* __restrict__ br,
               const float* __restrict__ wout, const float* __restrict__ bout,
               float* __restrict__ out, unsigned long long* __restrict__ xh)
{
  const int tid = threadIdx.x;
  // XCD swizzle: group g's two blocks are pb and pb+128 -> same pb&7 ->
  // same XCD under round-robin dispatch. Bijective on [0,256).
  const int pb = blockIdx.x;
  const int g  = (pb & 7) * 16 + ((pb >> 3) & 15);  // item [0,128)
  const int hf = pb >> 7;                           // half [0,2)
  const int c  = tid >> 2;                          // channel in half [0,128)
  const int rq = tid & 3;                           // row slice [0,4)
  const int cg = hf * 128 + c;                      // global channel

  // per parity: [0,64) u | [64,192) own h | [192,320) partner h
  __shared__ __align__(16) _Float16 uh[2][320];
  __shared__ float yred[2][16][17];
  __shared__ __align__(16) int wopk[2048];

  // ---- register-resident weights (160 pairs) ----
  int w2u[32], w2o[64], w2p[64];
#pragma unroll
  for (int gg = 0; gg < 4; ++gg) {
    const float* colp = (gg < 3) ? (kfiz + gg * HH + cg) : (kr + cg);
    const int cst = (gg < 3) ? 3 * HH : HH;
#pragma unroll
    for (int k = 0; k < 8; ++k) {       // u rows rq*16 + [0,16)
      f16x2 v;
      v.x = (_Float16)colp[(rq * 16 + 2 * k    ) * cst];
      v.y = (_Float16)colp[(rq * 16 + 2 * k + 1) * cst];
      w2u[gg * 8 + k] = h2b(v);
    }
#pragma unroll
    for (int k = 0; k < 16; ++k) {      // own + partner rows rq*32 + [0,32)
      f16x2 v;
      v.x = (_Float16)colp[(DD + hf * 128 + rq * 32 + 2 * k    ) * cst];
      v.y = (_Float16)colp[(DD + hf * 128 + rq * 32 + 2 * k + 1) * cst];
      w2o[gg * 16 + k] = h2b(v);
      f16x2 w;
      w.x = (_Float16)colp[(DD + (1 - hf) * 128 + rq * 32 + 2 * k    ) * cst];
      w.y = (_Float16)colp[(DD + (1 - hf) * 128 + rq * 32 + 2 * k + 1) * cst];
      w2p[gg * 16 + k] = h2b(w);
    }
  }
  const float bf_ = bfiz[0 * HH + cg];
  const float bi_ = bfiz[1 * HH + cg];
  const float bz_ = bfiz[2 * HH + cg];
  const float br_ = br[cg];

  // ---- W_out staged permuted: 16 chunks x 16 cols x 8 pairs ----
  for (int t = tid; t < 2048; t += 512) {
    const int k = t & 7, o = (t >> 3) & 15, jc = t >> 7;
    const int pos0 = jc * 16 + 2 * k, pos1 = pos0 + 1;
    const int ch0 = (pos0 < 128) ? hf * 128 + pos0 : (1 - hf) * 128 + (pos0 - 128);
    const int ch1 = (pos1 < 128) ? hf * 128 + pos1 : (1 - hf) * 128 + (pos1 - 128);
    f16x2 v;
    v.x = (_Float16)wout[ch0 * OO + hf * 16 + o];
    v.y = (_Float16)wout[ch1 * OO + hf * 16 + o];
    wopk[t] = h2b(v);
  }
  const float bo = (tid >= 448 && tid < 464) ? bout[hf * 16 + (tid - 448)] : 0.0f;

  // ---- state init ----
  float cs = x0[(size_t)g * 512 + 256 + cg];
  if (tid < 256) {   // h0: own half -> [64,192), partner half -> [192,320)
    const int ch = tid;
    const int pos = ((ch >> 7) == hf ? 64 : 192) + (ch & 127);
    uh[0][pos] = (_Float16)x0[(size_t)g * 512 + ch];
  }
  if (tid >= 448) {  // u_0
    uh[0][tid - 448] = (_Float16)u[(size_t)g * TT * DD + (tid - 448)];
  }
  __syncthreads();

  float af, ai, az, ar;
  UOWN(uh[0], af, ai, az, ar);

  for (int s = 0; s < TT; ++s) {
    const int cur = s & 1, nxt = cur ^ 1;

    // u_{s+1} issued early (lanes 192..256)
    float un = 0.0f;
    if (tid >= 192 && tid < 256 && s + 1 < TT) {
      un = u[((size_t)g * TT + s + 1) * DD + (tid - 192)];
    }

    // ---- A: partner dots ----
    PDOT(uh[cur], af, ai, az, ar);

    // ---- B: reduce (2-stage DPP) + activations ----
    XOR_ADD4(af); XOR_ADD4(ai); XOR_ADD4(az); XOR_ADD4(ar);
    const float f0 = sigm(af + bf_), i0 = sigm(ai + bi_);
    const float z0 = sigm(az + bz_), r0 = tanhf_(ar + br_);
    cs = f0 * cs + i0 * r0;
    const float hn = z0 * tanhf_(cs);

    // ---- C: publish (u64, 2 ch/word) + own-h LDS + u_{s+1} LDS ----
    const float hnn = __shfl_down(hn, 4);   // channel c+1's value (rq kept)
    if (rq == 0) {
      uh[nxt][64 + c] = (_Float16)hn;
      if (!(c & 1)) {
        const int pair = hf * 64 + (c >> 1);
        const unsigned long long tag = (unsigned long long)(s + 1) << 32;
        __hip_atomic_store(&xh[((size_t)nxt << 14) + (size_t)g * 128 + pair],
                           tag | pk32(hn, hnn),
                           __ATOMIC_RELAXED, __HIP_MEMORY_SCOPE_AGENT);
      }
    }
    if (tid >= 192 && tid < 256 && s + 1 < TT) {
      uh[nxt][tid - 192] = (_Float16)un;
    }
    BAR_LGKM();   // B1: LDS drain only; publish stores stay in flight

    // ---- D: shadow work, spec poll issued MID-D ----
    if (s >= 2 && tid >= 448 && tid < 464) {          // store y_{s-2}
      const int o = tid - 448;
      float ssum = bo;
#pragma unroll
      for (int k = 0; k < 16; ++k) ssum += yred[nxt][o][k];
      out[((size_t)g * TT + (s - 2)) * OO + hf * 16 + o] = ssum;
    }
    if (s >= 1 && tid >= 192 && tid < 448) {          // y partials for s-1
      const int idx = tid - 192;
      const int o = idx & 15, jc = idx >> 4;
      YPART(uh[cur], yred[cur][o][jc]);
    }
    unsigned long long pv = 0;
    const unsigned long long* pf = nullptr;
    if (tid < 64) {
      const int pidx = (1 - hf) * 64 + tid;           // partner pair
      pf = xh + ((size_t)nxt << 14) + (size_t)g * 128 + pidx;
    }
    if (s + 1 < TT) {                                  // u+own partials, s+1
      UOWN(uh[nxt], af, ai, az, ar);
    }
    if (tid < 64) {
      // mid-D spec issue: samples IC after partner publishes are visible,
      // returns ~end of D. sc0 sc1 = system-scope, bypass L1+L2.
      asm volatile("global_load_dwordx2 %0, %1, off sc0 sc1"
                   : "=v"(pv) : "v"(pf));
    }

    // ---- E: check spec; serial agent re-poll only if stale ----
    if (tid < 64) {
      asm volatile("s_waitcnt vmcnt(0)" : "+v"(pv) :: "memory");
      const unsigned want = (unsigned)(s + 1);
      while ((unsigned)(pv >> 32) != want)
        pv = __hip_atomic_load(pf, __ATOMIC_RELAXED, __HIP_MEMORY_SCOPE_AGENT);
      ((int*)&uh[nxt][192])[tid] = (int)(unsigned)pv;
    }
    BAR_LGKM();   // B2: LDS drain only; y/out stores stay in flight
  }

  // ---- epilogue: y_{TT-2} from yred[1]; y_{TT-1} from uh[0] ----
  if (tid >= 448 && tid < 464) {
    const int o = tid - 448;
    float ssum = bo;
#pragma unroll
    for (int k = 0; k < 16; ++k) ssum += yred[1][o][k];
    out[((size_t)g * TT + (TT - 2)) * OO + hf * 16 + o] = ssum;
  }
  if (tid >= 192 && tid < 448) {
    const int idx = tid - 192;
    const int o = idx & 15, jc = idx >> 4;
    YPART(uh[0], yred[0][o][jc]);
  }
  __syncthreads();
  if (tid >= 448 && tid < 464) {
    const int o = tid - 448;
    float ssum = bo;
#pragma unroll
    for (int k = 0; k < 16; ++k) ssum += yred[0][o][k];
    out[((size_t)g * TT + (TT - 1)) * OO + hf * 16 + o] = ssum;
  }
}

extern "C" void kernel_launch(void* const* d_in, const int* in_sizes, int n_in,
                              void* d_out, int out_size, void* d_ws, size_t ws_size,
                              hipStream_t stream) {
  const float* u    = (const float*)d_in[0];
  const float* x0   = (const float*)d_in[1];
  const float* kfiz = (const float*)d_in[2];
  const float* bfiz = (const float*)d_in[3];
  const float* kr   = (const float*)d_in[4];
  const float* br   = (const float*)d_in[5];
  const float* wout = (const float*)d_in[6];
  const float* bout = (const float*)d_in[7];
  float* out = (float*)d_out;
  // ws: xh[2 parity][128 item][128 pair] u64 = 256 KB. 0xAA poison -> tag
  // 0xAAAAAAAA never matches a version in [1,2048] -> no init, replay-safe.
  unsigned long long* xh = (unsigned long long*)d_ws;
  lstm_half<<<dim3(256), dim3(512), 0, stream>>>(
      u, x0, kfiz, bfiz, kr, br, wout, bout, out, xh);
}

// Round 9
// 2774.090 us; speedup vs baseline: 1.6772x; 1.0904x over previous
//
#include <hip/hip_runtime.h>
#include <cstdint>
#include <cstddef>

// SingleLayerLSTM: B=128, T=2048, D=64, H=256, O=32.
// v18 = v17 + (a) spec-poll issue moved BEFORE the shadow UOWN and
// (b) shfl-free u32 tagged publish.
// R8 post-mortem: v17 (width-2 groups) won (3262->3025) but stall/step
// grew 1330->1620cy: the spec poll was issued AFTER UOWN, so E's
// vmcnt(0) wait started immediately and ate the full load RTT with no
// compute cover; and the publish path serialized a shfl_down (~40cy).
//  (a) issue order for poll lanes: issue -> UOWN (~250-400cy cover) ->
//      vmcnt(0) -> tag check -> retry backstop. (R3-proven mechanism.)
//  (b) exchange word u32 = (s+1)<<16 | fp16(h): tag fits 16b (<=2048;
//      0xAAAA poison never matches) -> each rq==0 lane publishes its own
//      channel, no shfl. Poll: 128 lanes x 1 u32 (same lines as before).
//      Same parity/tag/replay-safety as the u64 scheme; ws = 256KB.
// Kept from v17/v16: width-2 groups (2 blocks/item, 128ch/block, 160
// weight pairs), XCD co-location swizzle (FETCH 531->169MB proven),
// 2-stage DPP reduce, raw lgkm barriers, agent-scope relaxed exchange.

#define HH 256
#define DD 64
#define TT 2048
#define OO 32

typedef _Float16 f16x2 __attribute__((ext_vector_type(2)));

__device__ __forceinline__ f16x2 b2h(int v) { return __builtin_bit_cast(f16x2, v); }
__device__ __forceinline__ int h2b(f16x2 v) { return __builtin_bit_cast(int, v); }

#if __has_builtin(__builtin_amdgcn_fdot2)
__device__ __forceinline__ float fdot2(f16x2 a, f16x2 b, float c) {
  return __builtin_amdgcn_fdot2(a, b, c, false);
}
#else
__device__ __forceinline__ float fdot2(f16x2 a, f16x2 b, float c) {
  return fmaf((float)a.y, (float)b.y, fmaf((float)a.x, (float)b.x, c));
}
#endif

__device__ __forceinline__ float frcp(float x) { return __builtin_amdgcn_rcpf(x); }
__device__ __forceinline__ float sigm(float x)  { return frcp(1.0f + __expf(-x)); }
__device__ __forceinline__ float tanhf_(float x){ return 1.0f - 2.0f * frcp(1.0f + __expf(2.0f * x)); }

// LDS-only drain + raw barrier: global loads/stores stay in flight.
#define BAR_LGKM() do { \
  asm volatile("s_waitcnt lgkmcnt(0)" ::: "memory"); \
  __builtin_amdgcn_s_barrier(); \
  asm volatile("" ::: "memory"); \
} while (0)

// DPP xor-add (ctrl must be constant -> template). bound_ctrl=true.
template <int CTRL>
__device__ __forceinline__ float dpp_add(float x) {
  const int t = __builtin_amdgcn_mov_dpp(__builtin_bit_cast(int, x),
                                         CTRL, 0xf, 0xf, true);
  return x + __builtin_bit_cast(float, t);
}
// 4-lane group (one quad): ^1 then ^2.
#define XOR_ADD4(x) do { \
  x = dpp_add<0xB1>(x);  /* quad_perm [1,0,3,2] : ^1 */ \
  x = dpp_add<0x4E>(x);  /* quad_perm [2,3,0,1] : ^2 */ \
} while (0)

// u(16 rows = 8 pairs/gate) + own-h(32 rows = 16 pairs/gate); overwrites F,I,Z,R
#define UOWN(X, F, I, Z, R) do { \
  int uv_[8], ov_[16]; \
  *(int4*)&uv_[0] = ((const int4*)&(X)[rq * 16])[0]; \
  *(int4*)&uv_[4] = ((const int4*)&(X)[rq * 16])[1]; \
  *(int4*)&ov_[0]  = ((const int4*)&(X)[64 + rq * 32])[0]; \
  *(int4*)&ov_[4]  = ((const int4*)&(X)[64 + rq * 32])[1]; \
  *(int4*)&ov_[8]  = ((const int4*)&(X)[64 + rq * 32])[2]; \
  *(int4*)&ov_[12] = ((const int4*)&(X)[64 + rq * 32])[3]; \
  float a0_ = 0.0f, a1_ = 0.0f, a2_ = 0.0f, a3_ = 0.0f; \
  _Pragma("unroll") for (int k_ = 0; k_ < 8; ++k_) { \
    a0_ = fdot2(b2h(w2u[ 0 + k_]), b2h(uv_[k_]), a0_); \
    a1_ = fdot2(b2h(w2u[ 8 + k_]), b2h(uv_[k_]), a1_); \
    a2_ = fdot2(b2h(w2u[16 + k_]), b2h(uv_[k_]), a2_); \
    a3_ = fdot2(b2h(w2u[24 + k_]), b2h(uv_[k_]), a3_); \
  } \
  _Pragma("unroll") for (int k_ = 0; k_ < 16; ++k_) { \
    a0_ = fdot2(b2h(w2o[ 0 + k_]), b2h(ov_[k_]), a0_); \
    a1_ = fdot2(b2h(w2o[16 + k_]), b2h(ov_[k_]), a1_); \
    a2_ = fdot2(b2h(w2o[32 + k_]), b2h(ov_[k_]), a2_); \
    a3_ = fdot2(b2h(w2o[48 + k_]), b2h(ov_[k_]), a3_); \
  } \
  F = a0_; I = a1_; Z = a2_; R = a3_; \
} while (0)

// partner-h (32 rows = 16 pairs/gate) accumulate into F,I,Z,R
#define PDOT(X, F, I, Z, R) do { \
  int pv_[16]; \
  *(int4*)&pv_[0]  = ((const int4*)&(X)[192 + rq * 32])[0]; \
  *(int4*)&pv_[4]  = ((const int4*)&(X)[192 + rq * 32])[1]; \
  *(int4*)&pv_[8]  = ((const int4*)&(X)[192 + rq * 32])[2]; \
  *(int4*)&pv_[12] = ((const int4*)&(X)[192 + rq * 32])[3]; \
  _Pragma("unroll") for (int k_ = 0; k_ < 16; ++k_) { \
    F = fdot2(b2h(w2p[ 0 + k_]), b2h(pv_[k_]), F); \
    I = fdot2(b2h(w2p[16 + k_]), b2h(pv_[k_]), I); \
    Z = fdot2(b2h(w2p[32 + k_]), b2h(pv_[k_]), Z); \
    R = fdot2(b2h(w2p[48 + k_]), b2h(pv_[k_]), R); \
  } \
} while (0)

// y-partials: h LDS positions [64,320), chunk jc of 16 elems, out col o.
#define YPART(X, OUTSLOT) do { \
  const int2* hq_ = (const int2*)&(X)[64 + jc * 16]; \
  int2 h0_ = hq_[0], h1_ = hq_[1], h2_ = hq_[2], h3_ = hq_[3]; \
  const int4* wp_ = (const int4*)&wopk[(jc * 16 + o) * 8]; \
  int4 wa_ = wp_[0], wb_ = wp_[1]; \
  float ya_ = 0.0f; \
  ya_ = fdot2(b2h(wa_.x), b2h(h0_.x), ya_); \
  ya_ = fdot2(b2h(wa_.y), b2h(h0_.y), ya_); \
  ya_ = fdot2(b2h(wa_.z), b2h(h1_.x), ya_); \
  ya_ = fdot2(b2h(wa_.w), b2h(h1_.y), ya_); \
  ya_ = fdot2(b2h(wb_.x), b2h(h2_.x), ya_); \
  ya_ = fdot2(b2h(wb_.y), b2h(h2_.y), ya_); \
  ya_ = fdot2(b2h(wb_.z), b2h(h3_.x), ya_); \
  ya_ = fdot2(b2h(wb_.w), b2h(h3_.y), ya_); \
  OUTSLOT = ya_; \
} while (0)

__global__ __launch_bounds__(512, 2)
void lstm_half(const float* __restrict__ u,    const float* __restrict__ x0,
               const float* __restrict__ kfiz, const float* __restrict__ bfiz,
               const float* __restrict__ kr,   const float* __restrict__ br,
               const float* __restrict__ wout, const float* __restrict__ bout,
               float* __restrict__ out, unsigned* __restrict__ xh)
{
  const int tid = threadIdx.x;
  // XCD swizzle: group g's two blocks are pb and pb+128 -> same pb&7 ->
  // same XCD under round-robin dispatch. Bijective on [0,256).
  const int pb = blockIdx.x;
  const int g  = (pb & 7) * 16 + ((pb >> 3) & 15);  // item [0,128)
  const int hf = pb >> 7;                           // half [0,2)
  const int c  = tid >> 2;                          // channel in half [0,128)
  const int rq = tid & 3;                           // row slice [0,4)
  const int cg = hf * 128 + c;                      // global channel

  // per parity: [0,64) u | [64,192) own h | [192,320) partner h
  __shared__ __align__(16) _Float16 uh[2][320];
  __shared__ float yred[2][16][17];
  __shared__ __align__(16) int wopk[2048];

  // ---- register-resident weights (160 pairs) ----
  int w2u[32], w2o[64], w2p[64];
#pragma unroll
  for (int gg = 0; gg < 4; ++gg) {
    const float* colp = (gg < 3) ? (kfiz + gg * HH + cg) : (kr + cg);
    const int cst = (gg < 3) ? 3 * HH : HH;
#pragma unroll
    for (int k = 0; k < 8; ++k) {       // u rows rq*16 + [0,16)
      f16x2 v;
      v.x = (_Float16)colp[(rq * 16 + 2 * k    ) * cst];
      v.y = (_Float16)colp[(rq * 16 + 2 * k + 1) * cst];
      w2u[gg * 8 + k] = h2b(v);
    }
#pragma unroll
    for (int k = 0; k < 16; ++k) {      // own + partner rows rq*32 + [0,32)
      f16x2 v;
      v.x = (_Float16)colp[(DD + hf * 128 + rq * 32 + 2 * k    ) * cst];
      v.y = (_Float16)colp[(DD + hf * 128 + rq * 32 + 2 * k + 1) * cst];
      w2o[gg * 16 + k] = h2b(v);
      f16x2 w;
      w.x = (_Float16)colp[(DD + (1 - hf) * 128 + rq * 32 + 2 * k    ) * cst];
      w.y = (_Float16)colp[(DD + (1 - hf) * 128 + rq * 32 + 2 * k + 1) * cst];
      w2p[gg * 16 + k] = h2b(w);
    }
  }
  const float bf_ = bfiz[0 * HH + cg];
  const float bi_ = bfiz[1 * HH + cg];
  const float bz_ = bfiz[2 * HH + cg];
  const float br_ = br[cg];

  // ---- W_out staged permuted: 16 chunks x 16 cols x 8 pairs ----
  for (int t = tid; t < 2048; t += 512) {
    const int k = t & 7, o = (t >> 3) & 15, jc = t >> 7;
    const int pos0 = jc * 16 + 2 * k, pos1 = pos0 + 1;
    const int ch0 = (pos0 < 128) ? hf * 128 + pos0 : (1 - hf) * 128 + (pos0 - 128);
    const int ch1 = (pos1 < 128) ? hf * 128 + pos1 : (1 - hf) * 128 + (pos1 - 128);
    f16x2 v;
    v.x = (_Float16)wout[ch0 * OO + hf * 16 + o];
    v.y = (_Float16)wout[ch1 * OO + hf * 16 + o];
    wopk[t] = h2b(v);
  }
  const float bo = (tid >= 448 && tid < 464) ? bout[hf * 16 + (tid - 448)] : 0.0f;

  // ---- state init ----
  float cs = x0[(size_t)g * 512 + 256 + cg];
  if (tid < 256) {   // h0: own half -> [64,192), partner half -> [192,320)
    const int ch = tid;
    const int pos = ((ch >> 7) == hf ? 64 : 192) + (ch & 127);
    uh[0][pos] = (_Float16)x0[(size_t)g * 512 + ch];
  }
  if (tid >= 448) {  // u_0
    uh[0][tid - 448] = (_Float16)u[(size_t)g * TT * DD + (tid - 448)];
  }
  __syncthreads();

  float af, ai, az, ar;
  UOWN(uh[0], af, ai, az, ar);

  for (int s = 0; s < TT; ++s) {
    const int cur = s & 1, nxt = cur ^ 1;

    // u_{s+1} issued early (lanes 192..256)
    float un = 0.0f;
    if (tid >= 192 && tid < 256 && s + 1 < TT) {
      un = u[((size_t)g * TT + s + 1) * DD + (tid - 192)];
    }

    // ---- A: partner dots ----
    PDOT(uh[cur], af, ai, az, ar);

    // ---- B: reduce (2-stage DPP) + activations ----
    XOR_ADD4(af); XOR_ADD4(ai); XOR_ADD4(az); XOR_ADD4(ar);
    const float f0 = sigm(af + bf_), i0 = sigm(ai + bi_);
    const float z0 = sigm(az + bz_), r0 = tanhf_(ar + br_);
    cs = f0 * cs + i0 * r0;
    const float hn = z0 * tanhf_(cs);

    // ---- C: publish (u32/ch, shfl-free) + own-h LDS + u_{s+1} LDS ----
    if (rq == 0) {
      uh[nxt][64 + c] = (_Float16)hn;
      const unsigned short hb = __builtin_bit_cast(unsigned short, (_Float16)hn);
      __hip_atomic_store(&xh[((size_t)nxt << 15) + (size_t)g * 256 + cg],
                         ((unsigned)(s + 1) << 16) | (unsigned)hb,
                         __ATOMIC_RELAXED, __HIP_MEMORY_SCOPE_AGENT);
    }
    if (tid >= 192 && tid < 256 && s + 1 < TT) {
      uh[nxt][tid - 192] = (_Float16)un;
    }
    BAR_LGKM();   // B1: LDS drain only; publish stores stay in flight

    // ---- D: spec poll issued FIRST, then shadow work covers its RTT ----
    unsigned pv = 0;
    const unsigned* pf = nullptr;
    if (tid < 128) {
      pf = xh + ((size_t)nxt << 15) + (size_t)g * 256 + (1 - hf) * 128 + tid;
      // system-scope load (bypass L1+L2): samples IC after partner
      // publishes land; UOWN below covers most of the load RTT.
      asm volatile("global_load_dword %0, %1, off sc0 sc1"
                   : "=v"(pv) : "v"(pf));
    }
    if (s >= 2 && tid >= 448 && tid < 464) {          // store y_{s-2}
      const int o = tid - 448;
      float ssum = bo;
#pragma unroll
      for (int k = 0; k < 16; ++k) ssum += yred[nxt][o][k];
      out[((size_t)g * TT + (s - 2)) * OO + hf * 16 + o] = ssum;
    }
    if (s >= 1 && tid >= 192 && tid < 448) {          // y partials for s-1
      const int idx = tid - 192;
      const int o = idx & 15, jc = idx >> 4;
      YPART(uh[cur], yred[cur][o][jc]);
    }
    if (s + 1 < TT) {                                  // u+own partials, s+1
      UOWN(uh[nxt], af, ai, az, ar);
    }

    // ---- E: check spec; serial agent re-poll only if stale ----
    if (tid < 128) {
      asm volatile("s_waitcnt vmcnt(0)" : "+v"(pv) :: "memory");
      const unsigned want = (unsigned)(s + 1);
      while ((pv >> 16) != want)
        pv = __hip_atomic_load(pf, __ATOMIC_RELAXED, __HIP_MEMORY_SCOPE_AGENT);
      ((unsigned short*)&uh[nxt][192])[tid] = (unsigned short)(pv & 0xFFFFu);
    }
    BAR_LGKM();   // B2: LDS drain only; y/out stores stay in flight
  }

  // ---- epilogue: y_{TT-2} from yred[1]; y_{TT-1} from uh[0] ----
  if (tid >= 448 && tid < 464) {
    const int o = tid - 448;
    float ssum = bo;
#pragma unroll
    for (int k = 0; k < 16; ++k) ssum += yred[1][o][k];
    out[((size_t)g * TT + (TT - 2)) * OO + hf * 16 + o] = ssum;
  }
  if (tid >= 192 && tid < 448) {
    const int idx = tid - 192;
    const int o = idx & 15, jc = idx >> 4;
    YPART(uh[0], yred[0][o][jc]);
  }
  __syncthreads();
  if (tid >= 448 && tid < 464) {
    const int o = tid - 448;
    float ssum = bo;
#pragma unroll
    for (int k = 0; k < 16; ++k) ssum += yred[0][o][k];
    out[((size_t)g * TT + (TT - 1)) * OO + hf * 16 + o] = ssum;
  }
}

extern "C" void kernel_launch(void* const* d_in, const int* in_sizes, int n_in,
                              void* d_out, int out_size, void* d_ws, size_t ws_size,
                              hipStream_t stream) {
  const float* u    = (const float*)d_in[0];
  const float* x0   = (const float*)d_in[1];
  const float* kfiz = (const float*)d_in[2];
  const float* bfiz = (const float*)d_in[3];
  const float* kr   = (const float*)d_in[4];
  const float* br   = (const float*)d_in[5];
  const float* wout = (const float*)d_in[6];
  const float* bout = (const float*)d_in[7];
  float* out = (float*)d_out;
  // ws: xh[2 parity][128 item][256 ch] u32 = 256 KB. Word = tag<<16 | fp16.
  // 0xAAAA poison tag never matches a version in [1,2048] -> no init,
  // graph-replay safe (same parity/tag-uniqueness argument as u64 scheme).
  unsigned* xh = (unsigned*)d_ws;
  lstm_half<<<dim3(256), dim3(512), 0, stream>>>(
      u, x0, kfiz, bfiz, kr, br, wout, bout, out, xh);
}

// Round 10
// 2766.267 us; speedup vs baseline: 1.6820x; 1.0028x over previous
//
#include <hip/hip_runtime.h>
#include <cstdint>
#include <cstddef>

// SingleLayerLSTM: B=128, T=2048, D=64, H=256, O=32.
// v19 = v18 + unroll-by-2 (compile-time cur/nxt parity) + hoisted
// per-lane exchange pointers.
// R9 post-mortem: v18 matched (3025->2774; VALUBusy 60.9). Step ~3394cy =
// busy ~2060 + stall ~1330. E-wait ~500cy is structural (RTT ~1000 >>
// cover window; early-issue can't beat it; dual-spec blocked by publish
// acks in poll waves' vmcnt). Width-2 structurally optimal (weights
// 320KB/item of RF force >=2 CUs/item). Remaining uncertainty: static
// VALU count (~880cy/SIMD) vs measured busy (~2060) -- loop/address
// overhead or dot2 issue rate. v19 tests the former:
//  - body unrolled x2: uh[cur]/uh[nxt] become uh[0]/uh[1] compile-time,
//    all parity addressing folds to immediates;
//  - publish addr (xp0/xp1) and poll addr (pf0/pf1) hoisted pre-loop.
// Everything else identical to v18: width-2 groups (2 blocks/item,
// 128ch/block, 160 weight-pair VGPRs), XCD co-location swizzle, 2-stage
// DPP reduce, u32 tagged publish (tag<<16|fp16, 0xAAAA poison -> no
// init, replay-safe), spec poll issued before UOWN, retry backstop,
// raw lgkm barriers.

#define HH 256
#define DD 64
#define TT 2048
#define OO 32

typedef _Float16 f16x2 __attribute__((ext_vector_type(2)));

__device__ __forceinline__ f16x2 b2h(int v) { return __builtin_bit_cast(f16x2, v); }
__device__ __forceinline__ int h2b(f16x2 v) { return __builtin_bit_cast(int, v); }

#if __has_builtin(__builtin_amdgcn_fdot2)
__device__ __forceinline__ float fdot2(f16x2 a, f16x2 b, float c) {
  return __builtin_amdgcn_fdot2(a, b, c, false);
}
#else
__device__ __forceinline__ float fdot2(f16x2 a, f16x2 b, float c) {
  return fmaf((float)a.y, (float)b.y, fmaf((float)a.x, (float)b.x, c));
}
#endif

__device__ __forceinline__ float frcp(float x) { return __builtin_amdgcn_rcpf(x); }
__device__ __forceinline__ float sigm(float x)  { return frcp(1.0f + __expf(-x)); }
__device__ __forceinline__ float tanhf_(float x){ return 1.0f - 2.0f * frcp(1.0f + __expf(2.0f * x)); }

// LDS-only drain + raw barrier: global loads/stores stay in flight.
#define BAR_LGKM() do { \
  asm volatile("s_waitcnt lgkmcnt(0)" ::: "memory"); \
  __builtin_amdgcn_s_barrier(); \
  asm volatile("" ::: "memory"); \
} while (0)

// DPP xor-add (ctrl must be constant -> template). bound_ctrl=true.
template <int CTRL>
__device__ __forceinline__ float dpp_add(float x) {
  const int t = __builtin_amdgcn_mov_dpp(__builtin_bit_cast(int, x),
                                         CTRL, 0xf, 0xf, true);
  return x + __builtin_bit_cast(float, t);
}
// 4-lane group (one quad): ^1 then ^2.
#define XOR_ADD4(x) do { \
  x = dpp_add<0xB1>(x);  /* quad_perm [1,0,3,2] : ^1 */ \
  x = dpp_add<0x4E>(x);  /* quad_perm [2,3,0,1] : ^2 */ \
} while (0)

// u(16 rows = 8 pairs/gate) + own-h(32 rows = 16 pairs/gate); overwrites F,I,Z,R
#define UOWN(X, F, I, Z, R) do { \
  int uv_[8], ov_[16]; \
  *(int4*)&uv_[0] = ((const int4*)&(X)[rq * 16])[0]; \
  *(int4*)&uv_[4] = ((const int4*)&(X)[rq * 16])[1]; \
  *(int4*)&ov_[0]  = ((const int4*)&(X)[64 + rq * 32])[0]; \
  *(int4*)&ov_[4]  = ((const int4*)&(X)[64 + rq * 32])[1]; \
  *(int4*)&ov_[8]  = ((const int4*)&(X)[64 + rq * 32])[2]; \
  *(int4*)&ov_[12] = ((const int4*)&(X)[64 + rq * 32])[3]; \
  float a0_ = 0.0f, a1_ = 0.0f, a2_ = 0.0f, a3_ = 0.0f; \
  _Pragma("unroll") for (int k_ = 0; k_ < 8; ++k_) { \
    a0_ = fdot2(b2h(w2u[ 0 + k_]), b2h(uv_[k_]), a0_); \
    a1_ = fdot2(b2h(w2u[ 8 + k_]), b2h(uv_[k_]), a1_); \
    a2_ = fdot2(b2h(w2u[16 + k_]), b2h(uv_[k_]), a2_); \
    a3_ = fdot2(b2h(w2u[24 + k_]), b2h(uv_[k_]), a3_); \
  } \
  _Pragma("unroll") for (int k_ = 0; k_ < 16; ++k_) { \
    a0_ = fdot2(b2h(w2o[ 0 + k_]), b2h(ov_[k_]), a0_); \
    a1_ = fdot2(b2h(w2o[16 + k_]), b2h(ov_[k_]), a1_); \
    a2_ = fdot2(b2h(w2o[32 + k_]), b2h(ov_[k_]), a2_); \
    a3_ = fdot2(b2h(w2o[48 + k_]), b2h(ov_[k_]), a3_); \
  } \
  F = a0_; I = a1_; Z = a2_; R = a3_; \
} while (0)

// partner-h (32 rows = 16 pairs/gate) accumulate into F,I,Z,R
#define PDOT(X, F, I, Z, R) do { \
  int pv_[16]; \
  *(int4*)&pv_[0]  = ((const int4*)&(X)[192 + rq * 32])[0]; \
  *(int4*)&pv_[4]  = ((const int4*)&(X)[192 + rq * 32])[1]; \
  *(int4*)&pv_[8]  = ((const int4*)&(X)[192 + rq * 32])[2]; \
  *(int4*)&pv_[12] = ((const int4*)&(X)[192 + rq * 32])[3]; \
  _Pragma("unroll") for (int k_ = 0; k_ < 16; ++k_) { \
    F = fdot2(b2h(w2p[ 0 + k_]), b2h(pv_[k_]), F); \
    I = fdot2(b2h(w2p[16 + k_]), b2h(pv_[k_]), I); \
    Z = fdot2(b2h(w2p[32 + k_]), b2h(pv_[k_]), Z); \
    R = fdot2(b2h(w2p[48 + k_]), b2h(pv_[k_]), R); \
  } \
} while (0)

// y-partials: h LDS positions [64,320), chunk jc of 16 elems, out col o.
#define YPART(X, OUTSLOT) do { \
  const int2* hq_ = (const int2*)&(X)[64 + jc * 16]; \
  int2 h0_ = hq_[0], h1_ = hq_[1], h2_ = hq_[2], h3_ = hq_[3]; \
  const int4* wp_ = (const int4*)&wopk[(jc * 16 + o) * 8]; \
  int4 wa_ = wp_[0], wb_ = wp_[1]; \
  float ya_ = 0.0f; \
  ya_ = fdot2(b2h(wa_.x), b2h(h0_.x), ya_); \
  ya_ = fdot2(b2h(wa_.y), b2h(h0_.y), ya_); \
  ya_ = fdot2(b2h(wa_.z), b2h(h1_.x), ya_); \
  ya_ = fdot2(b2h(wa_.w), b2h(h1_.y), ya_); \
  ya_ = fdot2(b2h(wb_.x), b2h(h2_.x), ya_); \
  ya_ = fdot2(b2h(wb_.y), b2h(h2_.y), ya_); \
  ya_ = fdot2(b2h(wb_.z), b2h(h3_.x), ya_); \
  ya_ = fdot2(b2h(wb_.w), b2h(h3_.y), ya_); \
  OUTSLOT = ya_; \
} while (0)

// One full timestep with compile-time parity. CURI/NXTI in {0,1}.
#define STEP_BODY(CURI, NXTI, S_) do { \
  /* u_{s+1} issued early (lanes 192..256) */ \
  float un = 0.0f; \
  if (tid >= 192 && tid < 256 && (S_) + 1 < TT) \
    un = u_lane[(size_t)((S_) + 1) * DD]; \
  /* A: partner dots */ \
  PDOT(uh[CURI], af, ai, az, ar); \
  /* B: reduce + activations */ \
  XOR_ADD4(af); XOR_ADD4(ai); XOR_ADD4(az); XOR_ADD4(ar); \
  const float f0 = sigm(af + bf_), i0 = sigm(ai + bi_); \
  const float z0 = sigm(az + bz_), r0 = tanhf_(ar + br_); \
  cs = f0 * cs + i0 * r0; \
  const float hn = z0 * tanhf_(cs); \
  /* C: publish (u32/ch, shfl-free) + own-h LDS + u LDS */ \
  if (rq == 0) { \
    uh[NXTI][64 + c] = (_Float16)hn; \
    const unsigned short hb = __builtin_bit_cast(unsigned short, (_Float16)hn); \
    __hip_atomic_store(xp##NXTI, ((unsigned)((S_) + 1) << 16) | (unsigned)hb, \
                       __ATOMIC_RELAXED, __HIP_MEMORY_SCOPE_AGENT); \
  } \
  if (tid >= 192 && tid < 256 && (S_) + 1 < TT) \
    uh[NXTI][tid - 192] = (_Float16)un; \
  BAR_LGKM(); /* B1 */ \
  /* D: spec poll first, shadow work covers its RTT */ \
  unsigned pv = 0; \
  if (tid < 128) \
    asm volatile("global_load_dword %0, %1, off sc0 sc1" \
                 : "=v"(pv) : "v"(pf##NXTI)); \
  if ((S_) >= 2 && tid >= 448 && tid < 464) { \
    const int o = tid - 448; \
    float ssum = bo; \
    _Pragma("unroll") for (int k = 0; k < 16; ++k) ssum += yred[NXTI][o][k]; \
    out_lane[(size_t)((S_) - 2) * OO] = ssum; \
  } \
  if ((S_) >= 1 && tid >= 192 && tid < 448) { \
    YPART(uh[CURI], yred[CURI][o][jc]); \
  } \
  if ((S_) + 1 < TT) { \
    UOWN(uh[NXTI], af, ai, az, ar); \
  } \
  /* E: check spec; serial re-poll only if stale */ \
  if (tid < 128) { \
    asm volatile("s_waitcnt vmcnt(0)" : "+v"(pv) :: "memory"); \
    const unsigned want = (unsigned)((S_) + 1); \
    while ((pv >> 16) != want) \
      pv = __hip_atomic_load(pf##NXTI, __ATOMIC_RELAXED, \
                             __HIP_MEMORY_SCOPE_AGENT); \
    ((unsigned short*)&uh[NXTI][192])[tid] = (unsigned short)(pv & 0xFFFFu); \
  } \
  BAR_LGKM(); /* B2 */ \
} while (0)

__global__ __launch_bounds__(512, 2)
void lstm_half(const float* __restrict__ u,    const float* __restrict__ x0,
               const float* __restrict__ kfiz, const float* __restrict__ bfiz,
               const float* __restrict__ kr,   const float* __restrict__ br,
               const float* __restrict__ wout, const float* __restrict__ bout,
               float* __restrict__ out, unsigned* __restrict__ xh)
{
  const int tid = threadIdx.x;
  // XCD swizzle: group g's two blocks are pb and pb+128 -> same pb&7 ->
  // same XCD under round-robin dispatch. Bijective on [0,256).
  const int pb = blockIdx.x;
  const int g  = (pb & 7) * 16 + ((pb >> 3) & 15);  // item [0,128)
  const int hf = pb >> 7;                           // half [0,2)
  const int c  = tid >> 2;                          // channel in half [0,128)
  const int rq = tid & 3;                           // row slice [0,4)
  const int cg = hf * 128 + c;                      // global channel

  // per parity: [0,64) u | [64,192) own h | [192,320) partner h
  __shared__ __align__(16) _Float16 uh[2][320];
  __shared__ float yred[2][16][17];
  __shared__ __align__(16) int wopk[2048];

  // ---- register-resident weights (160 pairs) ----
  int w2u[32], w2o[64], w2p[64];
#pragma unroll
  for (int gg = 0; gg < 4; ++gg) {
    const float* colp = (gg < 3) ? (kfiz + gg * HH + cg) : (kr + cg);
    const int cst = (gg < 3) ? 3 * HH : HH;
#pragma unroll
    for (int k = 0; k < 8; ++k) {       // u rows rq*16 + [0,16)
      f16x2 v;
      v.x = (_Float16)colp[(rq * 16 + 2 * k    ) * cst];
      v.y = (_Float16)colp[(rq * 16 + 2 * k + 1) * cst];
      w2u[gg * 8 + k] = h2b(v);
    }
#pragma unroll
    for (int k = 0; k < 16; ++k) {      // own + partner rows rq*32 + [0,32)
      f16x2 v;
      v.x = (_Float16)colp[(DD + hf * 128 + rq * 32 + 2 * k    ) * cst];
      v.y = (_Float16)colp[(DD + hf * 128 + rq * 32 + 2 * k + 1) * cst];
      w2o[gg * 16 + k] = h2b(v);
      f16x2 w;
      w.x = (_Float16)colp[(DD + (1 - hf) * 128 + rq * 32 + 2 * k    ) * cst];
      w.y = (_Float16)colp[(DD + (1 - hf) * 128 + rq * 32 + 2 * k + 1) * cst];
      w2p[gg * 16 + k] = h2b(w);
    }
  }
  const float bf_ = bfiz[0 * HH + cg];
  const float bi_ = bfiz[1 * HH + cg];
  const float bz_ = bfiz[2 * HH + cg];
  const float br_ = br[cg];

  // ---- W_out staged permuted: 16 chunks x 16 cols x 8 pairs ----
  for (int t = tid; t < 2048; t += 512) {
    const int k = t & 7, o = (t >> 3) & 15, jc = t >> 7;
    const int pos0 = jc * 16 + 2 * k, pos1 = pos0 + 1;
    const int ch0 = (pos0 < 128) ? hf * 128 + pos0 : (1 - hf) * 128 + (pos0 - 128);
    const int ch1 = (pos1 < 128) ? hf * 128 + pos1 : (1 - hf) * 128 + (pos1 - 128);
    f16x2 v;
    v.x = (_Float16)wout[ch0 * OO + hf * 16 + o];
    v.y = (_Float16)wout[ch1 * OO + hf * 16 + o];
    wopk[t] = h2b(v);
  }
  const float bo = (tid >= 448 && tid < 464) ? bout[hf * 16 + (tid - 448)] : 0.0f;

  // ---- hoisted per-lane pointers (loop-invariant) ----
  const float* u_lane = u + (size_t)g * TT * DD + (tid - 192);   // lanes 192..256
  float* out_lane = out + (size_t)g * TT * OO + hf * 16 + (tid - 448); // 448..464
  unsigned* xp0 = xh + (size_t)g * 256 + cg;                  // publish, parity 0
  unsigned* xp1 = xp0 + (1u << 15);                           // publish, parity 1
  const unsigned* pf0 = xh + (size_t)g * 256 + (1 - hf) * 128 + tid;  // poll, p0
  const unsigned* pf1 = pf0 + (1u << 15);                            // poll, p1
  const int o  = (tid - 192) & 15;   // YPART out col (lanes 192..448)
  const int jc = (tid - 192) >> 4;   // YPART chunk

  // ---- state init ----
  float cs = x0[(size_t)g * 512 + 256 + cg];
  if (tid < 256) {   // h0: own half -> [64,192), partner half -> [192,320)
    const int ch = tid;
    const int pos = ((ch >> 7) == hf ? 64 : 192) + (ch & 127);
    uh[0][pos] = (_Float16)x0[(size_t)g * 512 + ch];
  }
  if (tid >= 448) {  // u_0
    uh[0][tid - 448] = (_Float16)u[(size_t)g * TT * DD + (tid - 448)];
  }
  __syncthreads();

  float af, ai, az, ar;
  UOWN(uh[0], af, ai, az, ar);

  for (int s = 0; s < TT; s += 2) {
    STEP_BODY(0, 1, s);
    STEP_BODY(1, 0, s + 1);
  }

  // ---- epilogue: y_{TT-2} from yred[1]; y_{TT-1} from uh[0] ----
  if (tid >= 448 && tid < 464) {
    const int oo = tid - 448;
    float ssum = bo;
#pragma unroll
    for (int k = 0; k < 16; ++k) ssum += yred[1][oo][k];
    out[((size_t)g * TT + (TT - 2)) * OO + hf * 16 + oo] = ssum;
  }
  if (tid >= 192 && tid < 448) {
    YPART(uh[0], yred[0][o][jc]);
  }
  __syncthreads();
  if (tid >= 448 && tid < 464) {
    const int oo = tid - 448;
    float ssum = bo;
#pragma unroll
    for (int k = 0; k < 16; ++k) ssum += yred[0][oo][k];
    out[((size_t)g * TT + (TT - 1)) * OO + hf * 16 + oo] = ssum;
  }
}

extern "C" void kernel_launch(void* const* d_in, const int* in_sizes, int n_in,
                              void* d_out, int out_size, void* d_ws, size_t ws_size,
                              hipStream_t stream) {
  const float* u    = (const float*)d_in[0];
  const float* x0   = (const float*)d_in[1];
  const float* kfiz = (const float*)d_in[2];
  const float* bfiz = (const float*)d_in[3];
  const float* kr   = (const float*)d_in[4];
  const float* br   = (const float*)d_in[5];
  const float* wout = (const float*)d_in[6];
  const float* bout = (const float*)d_in[7];
  float* out = (float*)d_out;
  // ws: xh[2 parity][128 item][256 ch] u32 = 256 KB. Word = tag<<16 | fp16.
  // 0xAAAA poison tag never matches a version in [1,2048] -> no init,
  // graph-replay safe (same parity/tag-uniqueness argument as u64 scheme).
  unsigned* xh = (unsigned*)d_ws;
  lstm_half<<<dim3(256), dim3(512), 0, stream>>>(
      u, x0, kfiz, bfiz, kr, br, wout, bout, out, xh);
}